// Round 8
// baseline (528.635 us; speedup 1.0000x reference)
//
#include <hip/hip_runtime.h>

#define N_NODES 131072
#define N_EDGES 524288
#define K_TOP   65536
#define LN_EPS  1e-5f
#define N_TILES (N_NODES / 64)

typedef unsigned int u32;
typedef unsigned short u16;
typedef unsigned long long u64;

typedef __attribute__((ext_vector_type(8))) short bf8;
typedef __attribute__((ext_vector_type(4))) float f4;

// ---- ws layout (requires ws >= 40 MB) ----
#define ST_OFF    0             // SelState (~52KB, reserve 64KB)
#define CANON_OFF (64u<<10)     // canon + transposed weights (~461KB) -> [64K, 576K)
#define PART_OFF  (576u<<10)    // radix partials 256KB; +512B gcur[256]; +8KB zrow[64]
#define KEYS_OFF  (1u<<20)      // keys u64[N] = 1MB
#define TVAL_OFF  (2u<<20)      // N f32 = 512KB
#define KEPT_OFF  ((2u<<20)+(512u<<10)) // N u32 = 512KB
#define SBUF_OFF  (3u<<20)      // big buffer: N x 64 u32 = 32MB; pre-proj: pairs[2E] 4MB
#define DEG_OFF   (34u<<20)     // deg u32[N] = 512KB (inside SBUF tail; dead before proj)
#define OFF_OFF   (35u<<20)     // CSR off u32[N+1] = 512KB+4
#define ADJ_OFF   (36u<<20)     // CSR adj u32[2E] = 4MB -> ends 40M

// Big-buffer ping-pong (d_out doubles as scratch):
//   CSR: pairs=ws.SBUF (consumed by k_place before k_proj_down reuses SBUF)
//   down: S=ws.SBUF -> k_agg<1> -> H=d_out -> k_mlp<1> -> R=ws.SBUF
//   up:   k_proj_up(R=ws) -> S2=d_out -> k_agg<0> -> H=ws.SBUF -> k_mlp<0> -> d_out

// canonical parameter block offsets (bf16 elements)
#define C_DW1 0
#define C_DB1 16384
#define C_DW2 16512
#define C_DB2 32896
#define C_DW3 33024
#define C_DB3 49408
#define C_DG  49536
#define C_DBE 49664
#define C_UW1 49792
#define C_UB1 82560
#define C_UW2 82688
#define C_UB2 99072
#define C_UW3 99200
#define C_UB3 115584
#define C_UG  115712
#define C_UBE 115840
#define C_TOT 115968
// transposed weights WT[n][k] appended
#define CT_DW1 115968
#define CT_DW2 132352
#define CT_DW3 148736
#define CT_UW1 165120   /* [128][256] */
#define CT_UW2 197888
#define CT_UW3 214272
#define CT_TOT 230656

__device__ __forceinline__ float bflo(u32 u){ return __uint_as_float(u << 16); }
__device__ __forceinline__ float bfhi(u32 u){ return __uint_as_float(u & 0xFFFF0000u); }
__device__ __forceinline__ float bf2f(u16 v){ return __uint_as_float(((u32)v) << 16); }
__device__ __forceinline__ u32 f2bf(float f){
  u32 u = __float_as_uint(f);
  return (u + 0x7FFFu + ((u >> 16) & 1u)) >> 16;
}
__device__ __forceinline__ float gelu_f(float x){
  return 0.5f * x * (1.0f + erff(x * 0.7071067811865476f));
}
__device__ __forceinline__ float2 f2add(float2 a, float2 b){
  return make_float2(a.x + b.x, a.y + b.y);
}

// ---- swizzled LDS layout for [128 or 64 rows][16 chunks of 16B] matrices ----
__device__ __forceinline__ int swz16(int row, int cc){
  return row * 128 + ((cc ^ (row & 15)) * 8);
}

// A-fragment chunk builders (fragment lives in VGPRs; chunk cc = s*4+quad)
__device__ __forceinline__ bf8 ld_bf16_chunk(const u32* __restrict__ rowp, int s, int quad){
  uint4 v = *(const uint4*)(rowp + s * 16 + quad * 4);
  return __builtin_bit_cast(bf8, v);
}
__device__ __forceinline__ bf8 scale_bf16_chunk(const u32* __restrict__ rowp, int s, int quad, float tv){
  uint4 v = *(const uint4*)(rowp + s * 16 + quad * 4);
  uint4 q;
  q.x = f2bf(bflo(v.x) * tv) | (f2bf(bfhi(v.x) * tv) << 16);
  q.y = f2bf(bflo(v.y) * tv) | (f2bf(bfhi(v.y) * tv) << 16);
  q.z = f2bf(bflo(v.z) * tv) | (f2bf(bfhi(v.z) * tv) << 16);
  q.w = f2bf(bflo(v.w) * tv) | (f2bf(bfhi(v.w) * tv) << 16);
  return __builtin_bit_cast(bf8, q);
}
__device__ __forceinline__ bf8 cvt_f32_chunk(const float* __restrict__ rowp, int s, int quad, float tv){
  const float* p = rowp + s * 32 + quad * 8;
  float4 f0 = *(const float4*)p;
  float4 f1 = *(const float4*)(p + 4);
  uint4 q;
  q.x = f2bf(f0.x * tv) | (f2bf(f0.y * tv) << 16);
  q.y = f2bf(f0.z * tv) | (f2bf(f0.w * tv) << 16);
  q.z = f2bf(f1.x * tv) | (f2bf(f1.y * tv) << 16);
  q.w = f2bf(f1.z * tv) | (f2bf(f1.w * tv) << 16);
  return __builtin_bit_cast(bf8, q);
}

// 16x128 @ 128x128 GEMM step: A fragments in regs, B in swizzled LDS.
__device__ __forceinline__ void gemm_ab(const u16* ws, const bf8 a[4], int mn, int quad, f4 acc[8]){
  #pragma unroll
  for (int s = 0; s < 4; s++){
    #pragma unroll
    for (int j = 0; j < 8; j++){
      bf8 b = *(const bf8*)&ws[swz16(j * 16 + mn, s * 4 + quad)];
      acc[j] = __builtin_amdgcn_mfma_f32_16x16x32_bf16(a[s], b, acc[j], 0, 0, 0);
    }
  }
}

struct SelState {
  u64 prefix;
  u32 krem, eqcnt;
  int is_f32;
  u32 pad;
  double inv_norm;
  u32 eqlist[4096];
  u64 eqkey[4096];
};

struct P16 { const void* q[16]; };

// ---------------- dtype detection + state init (fused) ----------------
__global__ void k_detect(const u32* __restrict__ xw, SelState* st){
  int t = threadIdx.x;
  int cnt = 0;
  for (int i = t; i < 4096; i += 256){
    u32 w = xw[(size_t)i * 2048];
    u32 e = (w >> 23) & 0xFFu;
    if (e >= 97u && e <= 135u) cnt++;
  }
  __shared__ int sh[256];
  sh[t] = cnt; __syncthreads();
  for (int o = 128; o > 0; o >>= 1){ if (t < o) sh[t] += sh[t+o]; __syncthreads(); }
  if (t == 0){
    st->is_f32 = (sh[0] >= 3072) ? 1 : 0;
    st->prefix = 0; st->krem = K_TOP; st->eqcnt = 0;
  }
}

// ---------------- canon + transposed weights in ONE launch ----------------
__global__ void k_canon(P16 ps, const SelState* __restrict__ st, u16* __restrict__ canon){
  int i = blockIdx.x * 256 + threadIdx.x;
  if (i >= CT_TOT) return;
  int isf = st->is_f32;
  if (i < C_TOT){
    const int off[17] = {C_DW1,C_DB1,C_DW2,C_DB2,C_DW3,C_DB3,C_DG,C_DBE,
                         C_UW1,C_UB1,C_UW2,C_UB2,C_UW3,C_UB3,C_UG,C_UBE,C_TOT};
    int seg = 0;
    #pragma unroll
    for (int s2 = 0; s2 < 16; s2++) if (i >= off[s2+1]) seg = s2 + 1;
    int j = i - off[seg];
    if (isf) canon[i] = (u16)f2bf(((const float*)ps.q[seg])[j]);
    else     canon[i] = ((const u16*)ps.q[seg])[j];
  } else {
    const int dst[7] = {CT_DW1, CT_DW2, CT_DW3, CT_UW1, CT_UW2, CT_UW3, CT_TOT};
    const int wq[6]  = {0, 2, 4, 8, 10, 12};   // dW1,dW2,dW3,uW1,uW2,uW3 in ps.q
    int g = i;
    int seg = 0;
    #pragma unroll
    for (int s2 = 0; s2 < 6; s2++) if (g >= dst[s2+1]) seg = s2 + 1;
    int loc = g - dst[seg];
    int K = (seg == 3) ? 256 : 128;
    int n = loc / K, k = loc % K;
    int src = k * 128 + n;
    if (isf) canon[g] = (u16)f2bf(((const float*)ps.q[wq[seg]])[src]);
    else     canon[g] = ((const u16*)ps.q[wq[seg]])[src];
  }
}

// ---------------- score (pool-norm fused; same pairwise order as old tree) ----------------
__global__ __launch_bounds__(256) void k_score(const void* __restrict__ xraw, const void* __restrict__ praw,
                        const SelState* __restrict__ st,
                        u64* __restrict__ keys, float* __restrict__ tval){
  int t = threadIdx.x, lane = t & 63, w = t >> 6;
  int n = blockIdx.x * 4 + w;
  double d, ps;
  if (st->is_f32){
    const float* xf = (const float*)xraw + (size_t)n * 128;
    const float* pf = (const float*)praw;
    double p0 = (double)pf[lane], p1 = (double)pf[64 + lane];
    d  = (double)xf[lane] * p0 + (double)xf[64 + lane] * p1;
    ps = p0 * p0 + p1 * p1;
  } else {
    const u32* xw = (const u32*)xraw + (size_t)n * 64;
    const u32* pw = (const u32*)praw;
    u32 xx = xw[lane], pv = pw[lane];
    double p0 = (double)bflo(pv), p1 = (double)bfhi(pv);
    d  = (double)bflo(xx) * p0 + (double)bfhi(xx) * p1;
    ps = p0 * p0 + p1 * p1;
  }
  for (int o = 32; o > 0; o >>= 1){
    d  += __shfl_down(d,  o, 64);
    ps += __shfl_down(ps, o, 64);
  }
  if (lane == 0){
    double sc = d * (1.0 / sqrt(ps));
    u64 u = (u64)__double_as_longlong(sc);
    u64 key = (u & 0x8000000000000000ULL) ? ~u : (u | 0x8000000000000000ULL);
    keys[n] = key;
    tval[n] = tanhf((float)sc);
  }
}

// ---------------- contention-free 4-pass radix select (top 32 bits) ----------------
__global__ __launch_bounds__(256) void k_histp(const u64* __restrict__ keys,
                                               const SelState* __restrict__ st,
                                               u32* __restrict__ partial, int pass){
  __shared__ u32 h[256];
  int t = threadIdx.x;
  h[t] = 0;
  __syncthreads();
  u64 pref = st->prefix;
  int sh_d = 56 - 8 * pass;
  for (int n = blockIdx.x * 256 + t; n < N_NODES; n += 256 * 256){
    u64 k = keys[n];
    bool m = (pass == 0) ? true : ((k >> (sh_d + 8)) == pref);
    if (m) atomicAdd(&h[(u32)((k >> sh_d) & 255)], 1u);
  }
  __syncthreads();
  partial[blockIdx.x * 256 + t] = h[t];
}

__global__ void k_scanp(const u32* __restrict__ partial, SelState* st){
  __shared__ u32 tot[256];
  int t = threadIdx.x;
  u32 s = 0;
  for (int b = 0; b < 256; b++) s += partial[b * 256 + t];
  tot[t] = s;
  __syncthreads();
  if (t == 0){
    u32 target = st->krem;
    u32 cum = 0; int chosen = 255;
    for (int b = 255; b >= 0; b--){
      if (cum + tot[b] >= target){ chosen = b; break; }
      cum += tot[b];
    }
    st->prefix = (st->prefix << 8) | (u64)(u32)chosen;
    st->krem = target - cum;
  }
}

// mark + zero deg (deg has its own region; no overlay race)
__global__ void k_mark(const u64* __restrict__ keys, SelState* st, u32* __restrict__ kept,
                       u32* __restrict__ deg){
  int n = blockIdx.x * blockDim.x + threadIdx.x;
  u64 k = keys[n];
  u32 t32 = (u32)(k >> 32);
  u32 T = (u32)st->prefix;
  kept[n] = (t32 > T) ? 1u : 0u;
  deg[n] = 0u;
  if (t32 == T){
    u32 i = atomicAdd(&st->eqcnt, 1u);
    if (i < 4096){ st->eqlist[i] = (u32)n; st->eqkey[i] = k; }
  }
}

__global__ void k_tie(SelState* st, u32* __restrict__ kept){
  u32 m = st->eqcnt; if (m > 4096) m = 4096;
  u32 r = st->krem;
  for (u32 i = threadIdx.x; i < m; i += blockDim.x){
    u64 ki = st->eqkey[i]; u32 ii = st->eqlist[i];
    u32 rank = 0;
    for (u32 j = 0; j < m; j++){
      u64 kj = st->eqkey[j];
      rank += (kj > ki || (kj == ki && st->eqlist[j] < ii)) ? 1u : 0u;
    }
    if (rank < r) kept[ii] = 1u;
  }
}

// ---------------- CSR build (symmetrized adjacency), bucketed 2-pass ----------------
__global__ __launch_bounds__(256) void k_deg(const int* __restrict__ se, const int* __restrict__ re,
                                             u32* __restrict__ deg){
  int e = blockIdx.x * 256 + threadIdx.x;
  int s = se[e], r = re[e];
  atomicAdd(&deg[s], 1u);
  atomicAdd(&deg[r], 1u);
}

__global__ __launch_bounds__(256) void k_scan1(const u32* __restrict__ deg, u32* __restrict__ bsum){
  __shared__ u32 sh[256];
  int t = threadIdx.x;
  int base = blockIdx.x * 1024 + t * 4;
  u32 s = deg[base] + deg[base+1] + deg[base+2] + deg[base+3];
  sh[t] = s; __syncthreads();
  for (int o = 128; o > 0; o >>= 1){ if (t < o) sh[t] += sh[t+o]; __syncthreads(); }
  if (t == 0) bsum[blockIdx.x] = sh[0];
}

__global__ void k_scan2(u32* __restrict__ bsum){
  __shared__ u32 sh[128];
  int t = threadIdx.x;            // 128 threads
  u32 v = bsum[t];
  sh[t] = v; __syncthreads();
  for (int o = 1; o < 128; o <<= 1){
    u32 x = (t >= o) ? sh[t-o] : 0u;
    __syncthreads();
    sh[t] += x;
    __syncthreads();
  }
  bsum[t] = sh[t] - v;            // exclusive
}

// scan3 + gcur init + zero-row init (fused)
__global__ __launch_bounds__(256) void k_scan3(const u32* __restrict__ bsum,
                                               const u32* __restrict__ deg, u32* __restrict__ off,
                                               u32* __restrict__ gcur, u32* __restrict__ zrow){
  __shared__ u32 sh[256];
  int t = threadIdx.x;
  int base = blockIdx.x * 1024 + t * 4;
  u32 v0 = deg[base], v1 = deg[base+1], v2 = deg[base+2], v3 = deg[base+3];
  u32 s = v0 + v1 + v2 + v3;
  sh[t] = s; __syncthreads();
  for (int o = 1; o < 256; o <<= 1){
    u32 x = (t >= o) ? sh[t-o] : 0u;
    __syncthreads();
    sh[t] += x;
    __syncthreads();
  }
  u32 ex = sh[t] - s + bsum[blockIdx.x];
  if ((t & 127) == 0) gcur[base >> 9] = ex;   // base 512-aligned here; = off[base]
  off[base]   = ex; ex += v0;
  off[base+1] = ex; ex += v1;
  off[base+2] = ex; ex += v2;
  off[base+3] = ex;
  if (blockIdx.x == 0){
    if (t == 0) off[N_NODES] = 2u * N_EDGES;
    if (t < 64) zrow[t] = 0u;
  }
}

// Pass A: bin (target, neighbor) entries into 256 buckets via LDS, flush coalesced
// into pairs[] laid out at CSR bucket offsets. payload = (nlocal[9b] << 17) | nbr[17b]
__global__ __launch_bounds__(256) void k_bin(const int* __restrict__ se, const int* __restrict__ re,
                                             u32* __restrict__ gcur, u32* __restrict__ pairs){
  __shared__ u32 cnt[256], sc[256], base[256], cur[256], gpos[256];
  __shared__ u32 stage[8192];
  int t = threadIdx.x;
  cnt[t] = 0;
  __syncthreads();
  int e0 = blockIdx.x * 4096;
  for (int i = t; i < 4096; i += 256){
    int s = se[e0 + i], r = re[e0 + i];
    atomicAdd(&cnt[(u32)r >> 9], 1u);
    atomicAdd(&cnt[(u32)s >> 9], 1u);
  }
  __syncthreads();
  sc[t] = cnt[t];
  __syncthreads();
  for (int o = 1; o < 256; o <<= 1){
    u32 x = (t >= o) ? sc[t - o] : 0u;
    __syncthreads();
    sc[t] += x;
    __syncthreads();
  }
  base[t] = sc[t] - cnt[t];
  cur[t] = base[t];
  gpos[t] = atomicAdd(&gcur[t], cnt[t]);
  __syncthreads();
  for (int i = t; i < 4096; i += 256){
    u32 s = (u32)se[e0 + i], r = (u32)re[e0 + i];
    u32 b1 = r >> 9, p1 = ((r & 511u) << 17) | s;
    u32 b2 = s >> 9, p2 = ((s & 511u) << 17) | r;
    stage[atomicAdd(&cur[b1], 1u)] = p1;
    stage[atomicAdd(&cur[b2], 1u)] = p2;
  }
  __syncthreads();
  int lane = t & 63, wv = t >> 6;
  for (int b = wv; b < 256; b += 4){
    u32 n = cnt[b], src = base[b], dst = gpos[b];
    for (u32 i = lane; i < n; i += 64)
      pairs[dst + i] = stage[src + i];
  }
}

// Pass B: one block per bucket; place entries into exact CSR slots.
__global__ __launch_bounds__(256) void k_place(const u32* __restrict__ off,
                                               const u32* __restrict__ pairs,
                                               u32* __restrict__ adj){
  __shared__ u32 offl[513];
  __shared__ u32 curl[512];
  int b = blockIdx.x, t = threadIdx.x;
  for (int i = t; i < 513; i += 256) offl[i] = off[b * 512 + i];
  for (int i = t; i < 512; i += 256) curl[i] = 0;
  __syncthreads();
  u32 beg = offl[0], end = offl[512];
  for (u32 i = beg + t; i < end; i += 256){
    u32 p = pairs[i];
    u32 nl = p >> 17, m = p & 0x1FFFFu;
    u32 slot = offl[nl] + atomicAdd(&curl[nl], 1u);
    adj[slot] = m;
  }
}

// ---------------- persistent MFMA GEMM kernels ----------------
// (weights staged once, barrier-free tile loop, wave-private os)

// S[n] = kept[n] ? bf16(x[n]*tval[n] @ dW1) : 0
__global__ __launch_bounds__(256, 3) void k_proj_down(
    const void* __restrict__ xraw, const float* __restrict__ tval,
    const u16* __restrict__ W1T, const SelState* __restrict__ st,
    const u32* __restrict__ kept, u32* __restrict__ S)
{
  __shared__ u16 w1s[128 * 128];   // 32KB swizzled
  __shared__ u16 os[64 * 128];     // 16KB wave-private repack
  int t = threadIdx.x, lane = t & 63, wv = t >> 6;
  int m0 = wv * 16, mn = lane & 15, quad = lane >> 4;

  for (int i = t; i < 2048; i += 256){
    int row = i >> 4, cc = i & 15;
    *(uint4*)&w1s[swz16(row, cc)] = *(const uint4*)(W1T + row * 128 + cc * 8);
  }
  int isf = st->is_f32;
  __syncthreads();

  for (int tile = blockIdx.x; tile < N_TILES; tile += gridDim.x){
    int row0 = tile * 64;
    int arow = row0 + m0 + mn;
    float tv = tval[arow];
    bf8 a[4];
    if (isf){
      const float* xf = (const float*)xraw + (size_t)arow * 128;
      #pragma unroll
      for (int s = 0; s < 4; s++) a[s] = cvt_f32_chunk(xf, s, quad, tv);
    } else {
      const u32* xw = (const u32*)xraw + (size_t)arow * 64;
      #pragma unroll
      for (int s = 0; s < 4; s++) a[s] = scale_bf16_chunk(xw, s, quad, tv);
    }
    f4 acc[8];
    #pragma unroll
    for (int j = 0; j < 8; j++){ acc[j][0]=0.f; acc[j][1]=0.f; acc[j][2]=0.f; acc[j][3]=0.f; }
    gemm_ab(w1s, a, mn, quad, acc);

    #pragma unroll
    for (int j = 0; j < 8; j++){
      int c = j * 16 + mn;
      #pragma unroll
      for (int rg = 0; rg < 4; rg++){
        int row = m0 + quad * 4 + rg;
        os[row * 128 + ((c >> 3) ^ (row & 15)) * 8 + (c & 7)] = (u16)f2bf(acc[j][rg]);
      }
    }
    __builtin_amdgcn_wave_barrier();
    int rl = m0 + (lane >> 2), qt = lane & 3;
    u32 kp = kept[row0 + rl];
    u32* out = S + (size_t)(row0 + rl) * 64;
    #pragma unroll
    for (int i = 0; i < 4; i++){
      int cc = qt * 4 + i;
      uint4 w = *(const uint4*)&os[swz16(rl, cc)];
      if (!kp){ w.x = 0; w.y = 0; w.z = 0; w.w = 0; }
      *(uint4*)(out + cc * 4) = w;
    }
    __builtin_amdgcn_wave_barrier();  // readback before next tile overwrites os
  }
}

// S2[n] = bf16(R[n] @ uW1[0:128,:] + x[n] @ uW1[128:256,:])
__global__ __launch_bounds__(256, 2) void k_proj_up(
    const u32* __restrict__ R, const void* __restrict__ xraw,
    const u16* __restrict__ W1T, const SelState* __restrict__ st,
    u32* __restrict__ S2)
{
  __shared__ u16 was[128 * 128];   // uW1 rows, k 0:128
  __shared__ u16 wbs[128 * 128];   // uW1 rows, k 128:256
  __shared__ u16 os[64 * 128];
  int t = threadIdx.x, lane = t & 63, wv = t >> 6;
  int m0 = wv * 16, mn = lane & 15, quad = lane >> 4;

  for (int i = t; i < 2048; i += 256){
    int row = i >> 4, cc = i & 15;
    *(uint4*)&was[swz16(row, cc)] = *(const uint4*)(W1T + row * 256 + cc * 8);
    *(uint4*)&wbs[swz16(row, cc)] = *(const uint4*)(W1T + row * 256 + 128 + cc * 8);
  }
  int isf = st->is_f32;
  __syncthreads();

  for (int tile = blockIdx.x; tile < N_TILES; tile += gridDim.x){
    int row0 = tile * 64;
    int arow = row0 + m0 + mn;
    bf8 a[4];
    const u32* rp = R + (size_t)arow * 64;
    #pragma unroll
    for (int s = 0; s < 4; s++) a[s] = ld_bf16_chunk(rp, s, quad);
    f4 acc[8];
    #pragma unroll
    for (int j = 0; j < 8; j++){ acc[j][0]=0.f; acc[j][1]=0.f; acc[j][2]=0.f; acc[j][3]=0.f; }
    gemm_ab(was, a, mn, quad, acc);

    if (isf){
      const float* xf = (const float*)xraw + (size_t)arow * 128;
      #pragma unroll
      for (int s = 0; s < 4; s++) a[s] = cvt_f32_chunk(xf, s, quad, 1.0f);
    } else {
      const u32* xw = (const u32*)xraw + (size_t)arow * 64;
      #pragma unroll
      for (int s = 0; s < 4; s++) a[s] = ld_bf16_chunk(xw, s, quad);
    }
    gemm_ab(wbs, a, mn, quad, acc);

    #pragma unroll
    for (int j = 0; j < 8; j++){
      int c = j * 16 + mn;
      #pragma unroll
      for (int rg = 0; rg < 4; rg++){
        int row = m0 + quad * 4 + rg;
        os[row * 128 + ((c >> 3) ^ (row & 15)) * 8 + (c & 7)] = (u16)f2bf(acc[j][rg]);
      }
    }
    __builtin_amdgcn_wave_barrier();
    int rl = m0 + (lane >> 2), qt = lane & 3;
    u32* out = S2 + (size_t)(row0 + rl) * 64;
    #pragma unroll
    for (int i = 0; i < 4; i++){
      int cc = qt * 4 + i;
      *(uint4*)(out + cc * 4) = *(const uint4*)&os[swz16(rl, cc)];
    }
    __builtin_amdgcn_wave_barrier();
  }
}

// ---------------- dedicated high-occupancy pull-aggregation ----------------
// DOWN: non-kept neighbor rows are all-zero by construction; redirect their loads
// to a single L1-hot zero row (wave-uniform select) -> halves gather traffic,
// bit-identical result (x+0=x in f32). float2 accumulate invites v_pk_add_f32.
template<int IS_DOWN>
__device__ __forceinline__ const u32* rowsel(const u32* __restrict__ Smsg, u32 e,
                                             const u32* __restrict__ kept,
                                             const u32* __restrict__ zrow){
  const u32* p = Smsg + (size_t)e * 64;
  if (IS_DOWN) p = kept[e] ? p : zrow;
  return p;
}

template<int IS_DOWN>
__global__ __launch_bounds__(256, 4) void k_agg(
    const u32* __restrict__ Smsg, const u32* __restrict__ off, const u32* __restrict__ adj,
    const u16* __restrict__ cb1, const u32* __restrict__ kept,
    const u32* __restrict__ zrow, u32* __restrict__ H)
{
  int t = threadIdx.x, lane = t & 63, wv = t >> 6;
  float b1l = bf2f(cb1[2 * lane]), b1h = bf2f(cb1[2 * lane + 1]);
  int base = blockIdx.x * 16 + wv * 4;
  #pragma unroll 1
  for (int rr = 0; rr < 4; rr++){
    int n = base + rr;
    if (IS_DOWN && !kept[n]){ H[(size_t)n * 64 + lane] = 0u; continue; }
    u32 jb = off[n], je = off[n + 1];
    float2 a = make_float2(0.f, 0.f);
    u32 j = jb;
    for (; j + 8 <= je; j += 8){
      const u32* r0 = rowsel<IS_DOWN>(Smsg, adj[j],   kept, zrow);
      const u32* r1 = rowsel<IS_DOWN>(Smsg, adj[j+1], kept, zrow);
      const u32* r2 = rowsel<IS_DOWN>(Smsg, adj[j+2], kept, zrow);
      const u32* r3 = rowsel<IS_DOWN>(Smsg, adj[j+3], kept, zrow);
      const u32* r4 = rowsel<IS_DOWN>(Smsg, adj[j+4], kept, zrow);
      const u32* r5 = rowsel<IS_DOWN>(Smsg, adj[j+5], kept, zrow);
      const u32* r6 = rowsel<IS_DOWN>(Smsg, adj[j+6], kept, zrow);
      const u32* r7 = rowsel<IS_DOWN>(Smsg, adj[j+7], kept, zrow);
      u32 w0 = r0[lane], w1 = r1[lane], w2 = r2[lane], w3 = r3[lane];
      u32 w4 = r4[lane], w5 = r5[lane], w6 = r6[lane], w7 = r7[lane];
      float2 v0 = make_float2(bflo(w0), bfhi(w0));
      float2 v1 = make_float2(bflo(w1), bfhi(w1));
      float2 v2 = make_float2(bflo(w2), bfhi(w2));
      float2 v3 = make_float2(bflo(w3), bfhi(w3));
      float2 v4 = make_float2(bflo(w4), bfhi(w4));
      float2 v5 = make_float2(bflo(w5), bfhi(w5));
      float2 v6 = make_float2(bflo(w6), bfhi(w6));
      float2 v7 = make_float2(bflo(w7), bfhi(w7));
      a = f2add(a, f2add(f2add(f2add(v0, v1), f2add(v2, v3)),
                         f2add(f2add(v4, v5), f2add(v6, v7))));
    }
    for (; j + 4 <= je; j += 4){
      const u32* r0 = rowsel<IS_DOWN>(Smsg, adj[j],   kept, zrow);
      const u32* r1 = rowsel<IS_DOWN>(Smsg, adj[j+1], kept, zrow);
      const u32* r2 = rowsel<IS_DOWN>(Smsg, adj[j+2], kept, zrow);
      const u32* r3 = rowsel<IS_DOWN>(Smsg, adj[j+3], kept, zrow);
      u32 w0 = r0[lane], w1 = r1[lane], w2 = r2[lane], w3 = r3[lane];
      float2 v0 = make_float2(bflo(w0), bfhi(w0));
      float2 v1 = make_float2(bflo(w1), bfhi(w1));
      float2 v2 = make_float2(bflo(w2), bfhi(w2));
      float2 v3 = make_float2(bflo(w3), bfhi(w3));
      a = f2add(a, f2add(f2add(v0, v1), f2add(v2, v3)));
    }
    for (; j < je; j++){
      const u32* r0 = rowsel<IS_DOWN>(Smsg, adj[j], kept, zrow);
      u32 w = r0[lane];
      a = f2add(a, make_float2(bflo(w), bfhi(w)));
    }
    H[(size_t)n * 64 + lane] = f2bf(gelu_f(a.x + b1l)) | (f2bf(gelu_f(a.y + b1h)) << 16);
  }
}

// ---------------- persistent MFMA MLP tail ----------------
template<int IS_DOWN>
__global__ __launch_bounds__(256, 2) void k_mlp(
    const u32* __restrict__ H,
    const u16* __restrict__ cW2T, const u16* __restrict__ cb2,
    const u16* __restrict__ cW3T, const u16* __restrict__ cb3,
    const u16* __restrict__ cg, const u16* __restrict__ cbe,
    const u32* __restrict__ kept, const SelState* __restrict__ st,
    u32* __restrict__ Rout, void* __restrict__ fout)
{
  __shared__ u16 w2s[128 * 128];
  __shared__ u16 w3s[128 * 128];
  __shared__ u16 os[64 * 128];     // h2 staging, then output repack (wave-private)
  int t = threadIdx.x, lane = t & 63, wv = t >> 6;
  int m0 = wv * 16, mn = lane & 15, quad = lane >> 4;

  for (int i = t; i < 2048; i += 256){
    int row = i >> 4, cc = i & 15;
    *(uint4*)&w2s[swz16(row, cc)] = *(const uint4*)(cW2T + row * 128 + cc * 8);
    *(uint4*)&w3s[swz16(row, cc)] = *(const uint4*)(cW3T + row * 128 + cc * 8);
  }
  float b2v[8], b3v[8], gv[8], bev[8];
  #pragma unroll
  for (int j = 0; j < 8; j++){
    int c = j * 16 + mn;
    b2v[j] = bf2f(cb2[c]); b3v[j] = bf2f(cb3[c]);
    gv[j]  = bf2f(cg[c]);  bev[j] = bf2f(cbe[c]);
  }
  int isf = st->is_f32;
  __syncthreads();

  for (int tile = blockIdx.x; tile < N_TILES; tile += gridDim.x){
    int row0 = tile * 64;
    int arow = row0 + m0 + mn;

    bf8 a[4];
    const u32* hp = H + (size_t)arow * 64;
    #pragma unroll
    for (int s = 0; s < 4; s++) a[s] = ld_bf16_chunk(hp, s, quad);
    f4 acc[8];
    #pragma unroll
    for (int j = 0; j < 8; j++){ acc[j][0]=0.f; acc[j][1]=0.f; acc[j][2]=0.f; acc[j][3]=0.f; }
    gemm_ab(w2s, a, mn, quad, acc);

    #pragma unroll
    for (int j = 0; j < 8; j++){
      int c = j * 16 + mn;
      #pragma unroll
      for (int rg = 0; rg < 4; rg++){
        int row = m0 + quad * 4 + rg;
        os[row * 128 + ((c >> 3) ^ (row & 15)) * 8 + (c & 7)] = (u16)f2bf(gelu_f(acc[j][rg] + b2v[j]));
      }
    }
    __builtin_amdgcn_wave_barrier();

    #pragma unroll
    for (int s = 0; s < 4; s++) a[s] = *(const bf8*)&os[swz16(m0 + mn, s * 4 + quad)];
    #pragma unroll
    for (int j = 0; j < 8; j++){ acc[j][0]=0.f; acc[j][1]=0.f; acc[j][2]=0.f; acc[j][3]=0.f; }
    gemm_ab(w3s, a, mn, quad, acc);

    #pragma unroll
    for (int j = 0; j < 8; j++){
      #pragma unroll
      for (int rg = 0; rg < 4; rg++) acc[j][rg] += b3v[j];
    }
    float s1[4] = {0.f,0.f,0.f,0.f}, s2[4] = {0.f,0.f,0.f,0.f};
    #pragma unroll
    for (int j = 0; j < 8; j++){
      #pragma unroll
      for (int rg = 0; rg < 4; rg++){
        float v = acc[j][rg];
        s1[rg] += v; s2[rg] += v * v;
      }
    }
    #pragma unroll
    for (int o = 1; o < 16; o <<= 1){
      #pragma unroll
      for (int rg = 0; rg < 4; rg++){
        s1[rg] += __shfl_xor(s1[rg], o, 64);
        s2[rg] += __shfl_xor(s2[rg], o, 64);
      }
    }
    float mu[4], rs[4];
    #pragma unroll
    for (int rg = 0; rg < 4; rg++){
      mu[rg] = s1[rg] * 0.0078125f;
      float var = s2[rg] * 0.0078125f - mu[rg] * mu[rg];
      rs[rg] = rsqrtf(var + LN_EPS);
    }
    #pragma unroll
    for (int j = 0; j < 8; j++){
      #pragma unroll
      for (int rg = 0; rg < 4; rg++)
        acc[j][rg] = (acc[j][rg] - mu[rg]) * rs[rg] * gv[j] + bev[j];
    }

    if (!IS_DOWN && isf){
      float* fo = (float*)fout;
      #pragma unroll
      for (int j = 0; j < 8; j++){
        #pragma unroll
        for (int rg = 0; rg < 4; rg++)
          fo[(size_t)(row0 + m0 + quad * 4 + rg) * 128 + j * 16 + mn] = acc[j][rg];
      }
      continue;
    }

    __builtin_amdgcn_wave_barrier();
    #pragma unroll
    for (int j = 0; j < 8; j++){
      int c = j * 16 + mn;
      #pragma unroll
      for (int rg = 0; rg < 4; rg++){
        int row = m0 + quad * 4 + rg;
        os[row * 128 + ((c >> 3) ^ (row & 15)) * 8 + (c & 7)] = (u16)f2bf(acc[j][rg]);
      }
    }
    __builtin_amdgcn_wave_barrier();
    int rl = m0 + (lane >> 2), qt = lane & 3;
    u32 kp = IS_DOWN ? kept[row0 + rl] : 1u;
    u32* out = (IS_DOWN ? Rout : (u32*)fout) + (size_t)(row0 + rl) * 64;
    #pragma unroll
    for (int i = 0; i < 4; i++){
      int cc = qt * 4 + i;
      uint4 w = *(const uint4*)&os[swz16(rl, cc)];
      if (!kp){ w.x = 0; w.y = 0; w.z = 0; w.w = 0; }
      *(uint4*)(out + cc * 4) = w;
    }
    __builtin_amdgcn_wave_barrier();
  }
}

// ---------------- host launch ----------------

extern "C" void kernel_launch(void* const* d_in, const int* in_sizes, int n_in,
                              void* d_out, int out_size, void* d_ws, size_t ws_size,
                              hipStream_t stream)
{
  const void* x     = d_in[0];
  const int* eidx   = (const int*)d_in[1];
  const void* poolp = d_in[2];
  const int* senders = eidx;
  const int* receivers = eidx + N_EDGES;

  char* ws = (char*)d_ws;
  SelState* st = (SelState*)(ws + ST_OFF);
  u16*  canon  = (u16*) (ws + CANON_OFF);
  u32*  partial= (u32*) (ws + PART_OFF);   // radix partials; bsum/gcur/zrow overlays
  u64*  keys   = (u64*) (ws + KEYS_OFF);
  float* tval  = (float*)(ws + TVAL_OFF);
  u32*  kept   = (u32*) (ws + KEPT_OFF);
  u32*  Sbuf   = (u32*) (ws + SBUF_OFF);   // 32MB ws big-buffer (pairs, then messages)
  u32*  deg    = (u32*) (ws + DEG_OFF);    // own region (SBUF tail; dead before proj)
  u32*  off    = (u32*) (ws + OFF_OFF);
  u32*  adj    = (u32*) (ws + ADJ_OFF);
  u32*  bsum   = partial;
  u32*  gcur   = partial + 512;            // 256 u32 bucket cursors
  u32*  zrow   = partial + 2048;           // 256B zero row (for down-agg skip)
  u32*  pairs  = Sbuf;                     // 4MB staging (consumed before proj)
  u32*  Dbuf   = (u32*) d_out;             // 32MB d_out scratch region

  P16 ps;
  for (int i = 0; i < 16; i++) ps.q[i] = d_in[3 + i];

  k_detect<<<1, 256, 0, stream>>>((const u32*)x, st);   // + state init
  k_canon<<<(CT_TOT + 255) / 256, 256, 0, stream>>>(ps, st, canon);  // canon + WT fused
  k_score<<<N_NODES / 4, 256, 0, stream>>>(x, poolp, st, keys, tval); // + pool-norm fused
  for (int pass = 0; pass < 4; pass++){
    k_histp<<<256, 256, 0, stream>>>(keys, st, partial, pass);
    k_scanp<<<1, 256, 0, stream>>>(partial, st);
  }
  k_mark<<<N_NODES / 256, 256, 0, stream>>>(keys, st, kept, deg);    // + deg zero fused
  k_tie<<<1, 256, 0, stream>>>(st, kept);

  // ---- CSR build: deg -> scan -> bucketed 2-pass fill ----
  k_deg<<<N_EDGES / 256, 256, 0, stream>>>(senders, receivers, deg);
  k_scan1<<<128, 256, 0, stream>>>(deg, bsum);
  k_scan2<<<1, 128, 0, stream>>>(bsum);
  k_scan3<<<128, 256, 0, stream>>>(bsum, deg, off, gcur, zrow);      // + gcinit/zrow fused
  k_bin<<<N_EDGES / 4096, 256, 0, stream>>>(senders, receivers, gcur, pairs);
  k_place<<<256, 256, 0, stream>>>(off, pairs, adj);

  // ---- down conv: S(ws) -> agg H(d_out) -> MLP -> R(ws) ----
  k_proj_down<<<768, 256, 0, stream>>>(x, tval, canon + CT_DW1, st, kept, Sbuf);
  k_agg<1><<<N_NODES / 16, 256, 0, stream>>>(Sbuf, off, adj, canon + C_DB1, kept, zrow, Dbuf);
  k_mlp<1><<<512, 256, 0, stream>>>(Dbuf,
      canon + CT_DW2, canon + C_DB2, canon + CT_DW3, canon + C_DB3,
      canon + C_DG, canon + C_DBE, kept, st, Sbuf, nullptr);

  // ---- up conv: R(ws) -> S2(d_out) -> agg H(ws) -> MLP -> d_out ----
  k_proj_up<<<512, 256, 0, stream>>>(Sbuf, x, canon + CT_UW1, st, Dbuf);
  k_agg<0><<<N_NODES / 16, 256, 0, stream>>>(Dbuf, off, adj, canon + C_UB1, kept, zrow, Sbuf);
  k_mlp<0><<<512, 256, 0, stream>>>(Sbuf,
      canon + CT_UW2, canon + C_UB2, canon + CT_UW3, canon + C_UB3,
      canon + C_UG, canon + C_UBE, kept, st, nullptr, d_out);
}

// Round 9
// 449.833 us; speedup vs baseline: 1.1752x; 1.1752x over previous
//
#include <hip/hip_runtime.h>

#define N_NODES 131072
#define N_EDGES 524288
#define K_TOP   65536
#define LN_EPS  1e-5f
#define N_TILES (N_NODES / 64)
#define BCAP    5120u            /* bucket capacity: mean 4096 + 16 sigma */

typedef unsigned int u32;
typedef unsigned short u16;
typedef unsigned long long u64;

typedef __attribute__((ext_vector_type(8))) short bf8;
typedef __attribute__((ext_vector_type(4))) float f4;

// ---- ws layout (requires ws >= 40 MB) ----
#define ST_OFF    0             // SelState (~52KB, reserve 64KB)
#define CANON_OFF (64u<<10)     // canon + transposed weights (~461KB) -> [64K, 576K)
#define PART_OFF  (576u<<10)    // tots[4][256] (4KB) + gcur[256] (1KB)
#define KEYS_OFF  (1u<<20)      // keys u64[N] = 1MB; after k_tie reused as off/end u32[N] each
#define TVAL_OFF  (2u<<20)      // N f32 = 512KB
#define KEPT_OFF  ((2u<<20)+(512u<<10)) // N u32 = 512KB
#define SBUF_OFF  (3u<<20)      // big buffer: N x 64 u32 = 32MB; pre-proj: pairs 5MB
#define ADJ_OFF   (35u<<20)     // padded adj u32[256*BCAP] = 5MB -> ends 40M

// Big-buffer ping-pong (d_out doubles as scratch):
//   CSR: pairs=ws.SBUF (consumed by k_place before k_proj_down reuses SBUF)
//   down: S=ws.SBUF -> k_agg<1> -> H=d_out -> k_mlp<1> -> R=ws.SBUF
//   up:   k_proj_up(R=ws) -> S2=d_out -> k_agg<0> -> H=ws.SBUF -> k_mlp<0> -> d_out

// canonical parameter block offsets (bf16 elements)
#define C_DW1 0
#define C_DB1 16384
#define C_DW2 16512
#define C_DB2 32896
#define C_DW3 33024
#define C_DB3 49408
#define C_DG  49536
#define C_DBE 49664
#define C_UW1 49792
#define C_UB1 82560
#define C_UW2 82688
#define C_UB2 99072
#define C_UW3 99200
#define C_UB3 115584
#define C_UG  115712
#define C_UBE 115840
#define C_TOT 115968
// transposed weights WT[n][k] appended
#define CT_DW1 115968
#define CT_DW2 132352
#define CT_DW3 148736
#define CT_UW1 165120   /* [128][256] */
#define CT_UW2 197888
#define CT_UW3 214272
#define CT_TOT 230656

__device__ __forceinline__ float bflo(u32 u){ return __uint_as_float(u << 16); }
__device__ __forceinline__ float bfhi(u32 u){ return __uint_as_float(u & 0xFFFF0000u); }
__device__ __forceinline__ float bf2f(u16 v){ return __uint_as_float(((u32)v) << 16); }
__device__ __forceinline__ u32 f2bf(float f){
  u32 u = __float_as_uint(f);
  return (u + 0x7FFFu + ((u >> 16) & 1u)) >> 16;
}
__device__ __forceinline__ float gelu_f(float x){
  return 0.5f * x * (1.0f + erff(x * 0.7071067811865476f));
}
__device__ __forceinline__ float2 f2add(float2 a, float2 b){
  return make_float2(a.x + b.x, a.y + b.y);
}

// ---- swizzled LDS layout for [128 or 64 rows][16 chunks of 16B] matrices ----
__device__ __forceinline__ int swz16(int row, int cc){
  return row * 128 + ((cc ^ (row & 15)) * 8);
}

// A-fragment chunk builders (fragment lives in VGPRs; chunk cc = s*4+quad)
__device__ __forceinline__ bf8 ld_bf16_chunk(const u32* __restrict__ rowp, int s, int quad){
  uint4 v = *(const uint4*)(rowp + s * 16 + quad * 4);
  return __builtin_bit_cast(bf8, v);
}
__device__ __forceinline__ bf8 scale_bf16_chunk(const u32* __restrict__ rowp, int s, int quad, float tv){
  uint4 v = *(const uint4*)(rowp + s * 16 + quad * 4);
  uint4 q;
  q.x = f2bf(bflo(v.x) * tv) | (f2bf(bfhi(v.x) * tv) << 16);
  q.y = f2bf(bflo(v.y) * tv) | (f2bf(bfhi(v.y) * tv) << 16);
  q.z = f2bf(bflo(v.z) * tv) | (f2bf(bfhi(v.z) * tv) << 16);
  q.w = f2bf(bflo(v.w) * tv) | (f2bf(bfhi(v.w) * tv) << 16);
  return __builtin_bit_cast(bf8, q);
}
__device__ __forceinline__ bf8 cvt_f32_chunk(const float* __restrict__ rowp, int s, int quad, float tv){
  const float* p = rowp + s * 32 + quad * 8;
  float4 f0 = *(const float4*)p;
  float4 f1 = *(const float4*)(p + 4);
  uint4 q;
  q.x = f2bf(f0.x * tv) | (f2bf(f0.y * tv) << 16);
  q.y = f2bf(f0.z * tv) | (f2bf(f0.w * tv) << 16);
  q.z = f2bf(f1.x * tv) | (f2bf(f1.y * tv) << 16);
  q.w = f2bf(f1.z * tv) | (f2bf(f1.w * tv) << 16);
  return __builtin_bit_cast(bf8, q);
}

// 16x128 @ 128x128 GEMM step: A fragments in regs, B in swizzled LDS.
__device__ __forceinline__ void gemm_ab(const u16* ws, const bf8 a[4], int mn, int quad, f4 acc[8]){
  #pragma unroll
  for (int s = 0; s < 4; s++){
    #pragma unroll
    for (int j = 0; j < 8; j++){
      bf8 b = *(const bf8*)&ws[swz16(j * 16 + mn, s * 4 + quad)];
      acc[j] = __builtin_amdgcn_mfma_f32_16x16x32_bf16(a[s], b, acc[j], 0, 0, 0);
    }
  }
}

struct SelState {
  u64 prefix;
  u32 krem, eqcnt;
  int is_f32;
  u32 pad;
  double inv_norm;
  u32 eqlist[4096];
  u64 eqkey[4096];
};

struct P16 { const void* q[16]; };

// ---- shared radix-chain: suffix-scan tots[q] to get (chosen byte, new target) ----
// Integer-exact replica of the old serial k_scanp loop. Each caller block
// recomputes it redundantly from the per-pass global totals (256 values/pass).
__device__ __forceinline__ void chain_step(const u32* __restrict__ tots, int q,
                                           u32* sfx, u32* selb, int t,
                                           u64& pref, u32& target){
  sfx[t] = tots[q * 256 + t];
  __syncthreads();
  for (int o = 1; o < 256; o <<= 1){
    u32 x = (t + o < 256) ? sfx[t + o] : 0u;
    __syncthreads();
    sfx[t] += x;
    __syncthreads();
  }
  u32 above = (t == 255) ? 0u : sfx[t + 1];
  if (sfx[t] >= target && above < target){ selb[0] = (u32)t; selb[1] = target - above; }
  __syncthreads();
  pref = (pref << 8) | (u64)selb[0];
  target = selb[1];
  __syncthreads();
}

// ---------------- dtype detection + state init (fused) ----------------
__global__ void k_detect(const u32* __restrict__ xw, SelState* st){
  int t = threadIdx.x;
  int cnt = 0;
  for (int i = t; i < 4096; i += 256){
    u32 w = xw[(size_t)i * 2048];
    u32 e = (w >> 23) & 0xFFu;
    if (e >= 97u && e <= 135u) cnt++;
  }
  __shared__ int sh[256];
  sh[t] = cnt; __syncthreads();
  for (int o = 128; o > 0; o >>= 1){ if (t < o) sh[t] += sh[t+o]; __syncthreads(); }
  if (t == 0){
    st->is_f32 = (sh[0] >= 3072) ? 1 : 0;
    st->prefix = 0; st->krem = K_TOP; st->eqcnt = 0;
  }
}

// ---------------- canon + transposed weights + tots/gcur init (fused) ----------------
__global__ void k_canon(P16 ps, const SelState* __restrict__ st, u16* __restrict__ canon,
                        u32* __restrict__ tots, u32* __restrict__ gcur){
  int i = blockIdx.x * 256 + threadIdx.x;
  if (i < 1024) tots[i] = 0u;
  if (i < 256)  gcur[i] = (u32)i * BCAP;
  if (i >= CT_TOT) return;
  int isf = st->is_f32;
  if (i < C_TOT){
    const int off[17] = {C_DW1,C_DB1,C_DW2,C_DB2,C_DW3,C_DB3,C_DG,C_DBE,
                         C_UW1,C_UB1,C_UW2,C_UB2,C_UW3,C_UB3,C_UG,C_UBE,C_TOT};
    int seg = 0;
    #pragma unroll
    for (int s2 = 0; s2 < 16; s2++) if (i >= off[s2+1]) seg = s2 + 1;
    int j = i - off[seg];
    if (isf) canon[i] = (u16)f2bf(((const float*)ps.q[seg])[j]);
    else     canon[i] = ((const u16*)ps.q[seg])[j];
  } else {
    const int dst[7] = {CT_DW1, CT_DW2, CT_DW3, CT_UW1, CT_UW2, CT_UW3, CT_TOT};
    const int wq[6]  = {0, 2, 4, 8, 10, 12};   // dW1,dW2,dW3,uW1,uW2,uW3 in ps.q
    int g = i;
    int seg = 0;
    #pragma unroll
    for (int s2 = 0; s2 < 6; s2++) if (g >= dst[s2+1]) seg = s2 + 1;
    int loc = g - dst[seg];
    int K = (seg == 3) ? 256 : 128;
    int n = loc / K, k = loc % K;
    int src = k * 128 + n;
    if (isf) canon[g] = (u16)f2bf(((const float*)ps.q[wq[seg]])[src]);
    else     canon[g] = ((const u16*)ps.q[wq[seg]])[src];
  }
}

// ---------------- score (pool-norm fused; same pairwise order as old tree) ----------------
__global__ __launch_bounds__(256) void k_score(const void* __restrict__ xraw, const void* __restrict__ praw,
                        const SelState* __restrict__ st,
                        u64* __restrict__ keys, float* __restrict__ tval){
  int t = threadIdx.x, lane = t & 63, w = t >> 6;
  int n = blockIdx.x * 4 + w;
  double d, ps;
  if (st->is_f32){
    const float* xf = (const float*)xraw + (size_t)n * 128;
    const float* pf = (const float*)praw;
    double p0 = (double)pf[lane], p1 = (double)pf[64 + lane];
    d  = (double)xf[lane] * p0 + (double)xf[64 + lane] * p1;
    ps = p0 * p0 + p1 * p1;
  } else {
    const u32* xw = (const u32*)xraw + (size_t)n * 64;
    const u32* pw = (const u32*)praw;
    u32 xx = xw[lane], pv = pw[lane];
    double p0 = (double)bflo(pv), p1 = (double)bfhi(pv);
    d  = (double)bflo(xx) * p0 + (double)bfhi(xx) * p1;
    ps = p0 * p0 + p1 * p1;
  }
  for (int o = 32; o > 0; o >>= 1){
    d  += __shfl_down(d,  o, 64);
    ps += __shfl_down(ps, o, 64);
  }
  if (lane == 0){
    double sc = d * (1.0 / sqrt(ps));
    u64 u = (u64)__double_as_longlong(sc);
    u64 key = (u & 0x8000000000000000ULL) ? ~u : (u | 0x8000000000000000ULL);
    keys[n] = key;
    tval[n] = tanhf((float)sc);
  }
}

// ---------------- radix select: hist pass with in-kernel chain recompute ----------------
// tots[p][256] are global per-pass bin totals (atomically accumulated). Pass p
// derives the running prefix from tots[0..p-1] (integer-exact, redundant per block),
// eliminating the serial k_scanp kernels.
__global__ __launch_bounds__(256) void k_histp(const u64* __restrict__ keys,
                                               u32* __restrict__ tots, int pass){
  __shared__ u32 sfx[256];
  __shared__ u32 selb[2];
  __shared__ u32 h[256];
  int t = threadIdx.x;
  u64 pref = 0;
  u32 target = K_TOP;
  for (int q = 0; q < pass; q++)
    chain_step(tots, q, sfx, selb, t, pref, target);
  h[t] = 0;
  __syncthreads();
  int sh_d = 56 - 8 * pass;
  for (int n = blockIdx.x * 256 + t; n < N_NODES; n += 256 * 256){
    u64 k = keys[n];
    bool m = (pass == 0) ? true : ((k >> (sh_d + 8)) == pref);
    if (m) atomicAdd(&h[(u32)((k >> sh_d) & 255)], 1u);
  }
  __syncthreads();
  if (h[t]) atomicAdd(&tots[pass * 256 + t], h[t]);
}

// mark: recompute full 4-pass chain -> threshold T (top 32 bits)
__global__ __launch_bounds__(256) void k_mark(const u64* __restrict__ keys,
                                              const u32* __restrict__ tots,
                                              SelState* st, u32* __restrict__ kept){
  __shared__ u32 sfx[256];
  __shared__ u32 selb[2];
  int t = threadIdx.x;
  u64 pref = 0;
  u32 target = K_TOP;
  for (int q = 0; q < 4; q++)
    chain_step(tots, q, sfx, selb, t, pref, target);
  u32 T = (u32)pref;
  int n = blockIdx.x * 256 + t;
  u64 k = keys[n];
  u32 t32 = (u32)(k >> 32);
  kept[n] = (t32 > T) ? 1u : 0u;
  if (t32 == T){
    u32 i = atomicAdd(&st->eqcnt, 1u);
    if (i < 4096){ st->eqlist[i] = (u32)n; st->eqkey[i] = k; }
  }
}

__global__ __launch_bounds__(256) void k_tie(const u32* __restrict__ tots,
                                             SelState* st, u32* __restrict__ kept){
  __shared__ u32 sfx[256];
  __shared__ u32 selb[2];
  int t = threadIdx.x;
  u64 pref = 0;
  u32 target = K_TOP;
  for (int q = 0; q < 4; q++)
    chain_step(tots, q, sfx, selb, t, pref, target);
  u32 r = target;                       // krem after 4 passes
  u32 m = st->eqcnt; if (m > 4096) m = 4096;
  for (u32 i = t; i < m; i += 256){
    u64 ki = st->eqkey[i]; u32 ii = st->eqlist[i];
    u32 rank = 0;
    for (u32 j = 0; j < m; j++){
      u64 kj = st->eqkey[j];
      rank += (kj > ki || (kj == ki && st->eqlist[j] < ii)) ? 1u : 0u;
    }
    if (rank < r) kept[ii] = 1u;
  }
}

// ---------------- CSR build: fixed-capacity buckets, no deg/scan kernels ----------------
// Pass A: bin (target, neighbor) entries into 256 padded bucket regions via LDS,
// flush coalesced. payload = (nlocal[9b] << 17) | nbr[17b]
__global__ __launch_bounds__(256) void k_bin(const int* __restrict__ se, const int* __restrict__ re,
                                             u32* __restrict__ gcur, u32* __restrict__ pairs){
  __shared__ u32 cnt[256], sc[256], base[256], cur[256], gpos[256];
  __shared__ u32 stage[8192];
  int t = threadIdx.x;
  cnt[t] = 0;
  __syncthreads();
  int e0 = blockIdx.x * 4096;
  for (int i = t; i < 4096; i += 256){
    int s = se[e0 + i], r = re[e0 + i];
    atomicAdd(&cnt[(u32)r >> 9], 1u);
    atomicAdd(&cnt[(u32)s >> 9], 1u);
  }
  __syncthreads();
  sc[t] = cnt[t];
  __syncthreads();
  for (int o = 1; o < 256; o <<= 1){
    u32 x = (t >= o) ? sc[t - o] : 0u;
    __syncthreads();
    sc[t] += x;
    __syncthreads();
  }
  base[t] = sc[t] - cnt[t];
  cur[t] = base[t];
  gpos[t] = atomicAdd(&gcur[t], cnt[t]);
  __syncthreads();
  for (int i = t; i < 4096; i += 256){
    u32 s = (u32)se[e0 + i], r = (u32)re[e0 + i];
    u32 b1 = r >> 9, p1 = ((r & 511u) << 17) | s;
    u32 b2 = s >> 9, p2 = ((s & 511u) << 17) | r;
    stage[atomicAdd(&cur[b1], 1u)] = p1;
    stage[atomicAdd(&cur[b2], 1u)] = p2;
  }
  __syncthreads();
  int lane = t & 63, wv = t >> 6;
  for (int b = wv; b < 256; b += 4){
    u32 n = cnt[b], src = base[b], dst = gpos[b];
    for (u32 i = lane; i < n; i += 64)
      pairs[dst + i] = stage[src + i];
  }
}

// Pass B: one block per bucket. Count per-node in LDS, scan -> node offsets,
// write off[]/end[], then place entries into exact slots (bucket-local window).
__global__ __launch_bounds__(256) void k_place(const u32* __restrict__ gcur,
                                               const u32* __restrict__ pairs,
                                               u32* __restrict__ adj,
                                               u32* __restrict__ off, u32* __restrict__ end){
  __shared__ u32 cnt[512], cur[512], lo[512], ex2[256];
  int b = blockIdx.x, t = threadIdx.x;
  u32 base = (u32)b * BCAP;
  u32 total = gcur[b] - base;
  cnt[t] = 0; cnt[t + 256] = 0; cur[t] = 0; cur[t + 256] = 0;
  __syncthreads();
  for (u32 i = t; i < total; i += 256)
    atomicAdd(&cnt[pairs[base + i] >> 17], 1u);
  __syncthreads();
  u32 c0 = cnt[2 * t], c1 = cnt[2 * t + 1];
  ex2[t] = c0 + c1;
  __syncthreads();
  for (int o = 1; o < 256; o <<= 1){
    u32 x = (t >= o) ? ex2[t - o] : 0u;
    __syncthreads();
    ex2[t] += x;
    __syncthreads();
  }
  u32 e0 = ex2[t] - c0 - c1;           // exclusive prefix for node 2t
  int n0 = b * 512 + 2 * t;
  off[n0]     = base + e0;        end[n0]     = base + e0 + c0;
  off[n0 + 1] = base + e0 + c0;   end[n0 + 1] = base + e0 + c0 + c1;
  lo[2 * t] = e0; lo[2 * t + 1] = e0 + c0;
  __syncthreads();
  for (u32 i = t; i < total; i += 256){
    u32 p = pairs[base + i];
    u32 nl = p >> 17;
    u32 slot = base + lo[nl] + atomicAdd(&cur[nl], 1u);
    adj[slot] = p & 0x1FFFFu;
  }
}

// ---------------- persistent MFMA GEMM kernels ----------------
// (weights staged once, barrier-free tile loop, wave-private os)

// S[n] = kept[n] ? bf16(x[n]*tval[n] @ dW1) : 0
__global__ __launch_bounds__(256, 3) void k_proj_down(
    const void* __restrict__ xraw, const float* __restrict__ tval,
    const u16* __restrict__ W1T, const SelState* __restrict__ st,
    const u32* __restrict__ kept, u32* __restrict__ S)
{
  __shared__ u16 w1s[128 * 128];   // 32KB swizzled
  __shared__ u16 os[64 * 128];     // 16KB wave-private repack
  int t = threadIdx.x, lane = t & 63, wv = t >> 6;
  int m0 = wv * 16, mn = lane & 15, quad = lane >> 4;

  for (int i = t; i < 2048; i += 256){
    int row = i >> 4, cc = i & 15;
    *(uint4*)&w1s[swz16(row, cc)] = *(const uint4*)(W1T + row * 128 + cc * 8);
  }
  int isf = st->is_f32;
  __syncthreads();

  for (int tile = blockIdx.x; tile < N_TILES; tile += gridDim.x){
    int row0 = tile * 64;
    int arow = row0 + m0 + mn;
    float tv = tval[arow];
    bf8 a[4];
    if (isf){
      const float* xf = (const float*)xraw + (size_t)arow * 128;
      #pragma unroll
      for (int s = 0; s < 4; s++) a[s] = cvt_f32_chunk(xf, s, quad, tv);
    } else {
      const u32* xw = (const u32*)xraw + (size_t)arow * 64;
      #pragma unroll
      for (int s = 0; s < 4; s++) a[s] = scale_bf16_chunk(xw, s, quad, tv);
    }
    f4 acc[8];
    #pragma unroll
    for (int j = 0; j < 8; j++){ acc[j][0]=0.f; acc[j][1]=0.f; acc[j][2]=0.f; acc[j][3]=0.f; }
    gemm_ab(w1s, a, mn, quad, acc);

    #pragma unroll
    for (int j = 0; j < 8; j++){
      int c = j * 16 + mn;
      #pragma unroll
      for (int rg = 0; rg < 4; rg++){
        int row = m0 + quad * 4 + rg;
        os[row * 128 + ((c >> 3) ^ (row & 15)) * 8 + (c & 7)] = (u16)f2bf(acc[j][rg]);
      }
    }
    __builtin_amdgcn_wave_barrier();
    int rl = m0 + (lane >> 2), qt = lane & 3;
    u32 kp = kept[row0 + rl];
    u32* out = S + (size_t)(row0 + rl) * 64;
    #pragma unroll
    for (int i = 0; i < 4; i++){
      int cc = qt * 4 + i;
      uint4 w = *(const uint4*)&os[swz16(rl, cc)];
      if (!kp){ w.x = 0; w.y = 0; w.z = 0; w.w = 0; }
      *(uint4*)(out + cc * 4) = w;
    }
    __builtin_amdgcn_wave_barrier();  // readback before next tile overwrites os
  }
}

// S2[n] = bf16(R[n] @ uW1[0:128,:] + x[n] @ uW1[128:256,:])
__global__ __launch_bounds__(256, 2) void k_proj_up(
    const u32* __restrict__ R, const void* __restrict__ xraw,
    const u16* __restrict__ W1T, const SelState* __restrict__ st,
    u32* __restrict__ S2)
{
  __shared__ u16 was[128 * 128];   // uW1 rows, k 0:128
  __shared__ u16 wbs[128 * 128];   // uW1 rows, k 128:256
  __shared__ u16 os[64 * 128];
  int t = threadIdx.x, lane = t & 63, wv = t >> 6;
  int m0 = wv * 16, mn = lane & 15, quad = lane >> 4;

  for (int i = t; i < 2048; i += 256){
    int row = i >> 4, cc = i & 15;
    *(uint4*)&was[swz16(row, cc)] = *(const uint4*)(W1T + row * 256 + cc * 8);
    *(uint4*)&wbs[swz16(row, cc)] = *(const uint4*)(W1T + row * 256 + 128 + cc * 8);
  }
  int isf = st->is_f32;
  __syncthreads();

  for (int tile = blockIdx.x; tile < N_TILES; tile += gridDim.x){
    int row0 = tile * 64;
    int arow = row0 + m0 + mn;
    bf8 a[4];
    const u32* rp = R + (size_t)arow * 64;
    #pragma unroll
    for (int s = 0; s < 4; s++) a[s] = ld_bf16_chunk(rp, s, quad);
    f4 acc[8];
    #pragma unroll
    for (int j = 0; j < 8; j++){ acc[j][0]=0.f; acc[j][1]=0.f; acc[j][2]=0.f; acc[j][3]=0.f; }
    gemm_ab(was, a, mn, quad, acc);

    if (isf){
      const float* xf = (const float*)xraw + (size_t)arow * 128;
      #pragma unroll
      for (int s = 0; s < 4; s++) a[s] = cvt_f32_chunk(xf, s, quad, 1.0f);
    } else {
      const u32* xw = (const u32*)xraw + (size_t)arow * 64;
      #pragma unroll
      for (int s = 0; s < 4; s++) a[s] = ld_bf16_chunk(xw, s, quad);
    }
    gemm_ab(wbs, a, mn, quad, acc);

    #pragma unroll
    for (int j = 0; j < 8; j++){
      int c = j * 16 + mn;
      #pragma unroll
      for (int rg = 0; rg < 4; rg++){
        int row = m0 + quad * 4 + rg;
        os[row * 128 + ((c >> 3) ^ (row & 15)) * 8 + (c & 7)] = (u16)f2bf(acc[j][rg]);
      }
    }
    __builtin_amdgcn_wave_barrier();
    int rl = m0 + (lane >> 2), qt = lane & 3;
    u32* out = S2 + (size_t)(row0 + rl) * 64;
    #pragma unroll
    for (int i = 0; i < 4; i++){
      int cc = qt * 4 + i;
      *(uint4*)(out + cc * 4) = *(const uint4*)&os[swz16(rl, cc)];
    }
    __builtin_amdgcn_wave_barrier();
  }
}

// ---------------- dedicated high-occupancy pull-aggregation ----------------
template<int IS_DOWN>
__global__ __launch_bounds__(256, 4) void k_agg(
    const u32* __restrict__ Smsg, const u32* __restrict__ off, const u32* __restrict__ end,
    const u32* __restrict__ adj,
    const u16* __restrict__ cb1, const u32* __restrict__ kept,
    u32* __restrict__ H)
{
  int t = threadIdx.x, lane = t & 63, wv = t >> 6;
  float b1l = bf2f(cb1[2 * lane]), b1h = bf2f(cb1[2 * lane + 1]);
  int base = blockIdx.x * 16 + wv * 4;
  #pragma unroll 1
  for (int rr = 0; rr < 4; rr++){
    int n = base + rr;
    if (IS_DOWN && !kept[n]){ H[(size_t)n * 64 + lane] = 0u; continue; }
    u32 jb = off[n], je = end[n];
    float2 a = make_float2(0.f, 0.f);
    u32 j = jb;
    for (; j + 8 <= je; j += 8){
      u32 e0 = adj[j],   e1 = adj[j+1], e2 = adj[j+2], e3 = adj[j+3];
      u32 e4 = adj[j+4], e5 = adj[j+5], e6 = adj[j+6], e7 = adj[j+7];
      u32 w0 = Smsg[(size_t)e0 * 64 + lane];
      u32 w1 = Smsg[(size_t)e1 * 64 + lane];
      u32 w2 = Smsg[(size_t)e2 * 64 + lane];
      u32 w3 = Smsg[(size_t)e3 * 64 + lane];
      u32 w4 = Smsg[(size_t)e4 * 64 + lane];
      u32 w5 = Smsg[(size_t)e5 * 64 + lane];
      u32 w6 = Smsg[(size_t)e6 * 64 + lane];
      u32 w7 = Smsg[(size_t)e7 * 64 + lane];
      float2 v0 = make_float2(bflo(w0), bfhi(w0));
      float2 v1 = make_float2(bflo(w1), bfhi(w1));
      float2 v2 = make_float2(bflo(w2), bfhi(w2));
      float2 v3 = make_float2(bflo(w3), bfhi(w3));
      float2 v4 = make_float2(bflo(w4), bfhi(w4));
      float2 v5 = make_float2(bflo(w5), bfhi(w5));
      float2 v6 = make_float2(bflo(w6), bfhi(w6));
      float2 v7 = make_float2(bflo(w7), bfhi(w7));
      a = f2add(a, f2add(f2add(f2add(v0, v1), f2add(v2, v3)),
                         f2add(f2add(v4, v5), f2add(v6, v7))));
    }
    for (; j + 4 <= je; j += 4){
      u32 e0 = adj[j], e1 = adj[j+1], e2 = adj[j+2], e3 = adj[j+3];
      u32 w0 = Smsg[(size_t)e0 * 64 + lane];
      u32 w1 = Smsg[(size_t)e1 * 64 + lane];
      u32 w2 = Smsg[(size_t)e2 * 64 + lane];
      u32 w3 = Smsg[(size_t)e3 * 64 + lane];
      float2 v0 = make_float2(bflo(w0), bfhi(w0));
      float2 v1 = make_float2(bflo(w1), bfhi(w1));
      float2 v2 = make_float2(bflo(w2), bfhi(w2));
      float2 v3 = make_float2(bflo(w3), bfhi(w3));
      a = f2add(a, f2add(f2add(v0, v1), f2add(v2, v3)));
    }
    for (; j < je; j++){
      u32 w = Smsg[(size_t)adj[j] * 64 + lane];
      a = f2add(a, make_float2(bflo(w), bfhi(w)));
    }
    H[(size_t)n * 64 + lane] = f2bf(gelu_f(a.x + b1l)) | (f2bf(gelu_f(a.y + b1h)) << 16);
  }
}

// ---------------- persistent MFMA MLP tail ----------------
template<int IS_DOWN>
__global__ __launch_bounds__(256, 2) void k_mlp(
    const u32* __restrict__ H,
    const u16* __restrict__ cW2T, const u16* __restrict__ cb2,
    const u16* __restrict__ cW3T, const u16* __restrict__ cb3,
    const u16* __restrict__ cg, const u16* __restrict__ cbe,
    const u32* __restrict__ kept, const SelState* __restrict__ st,
    u32* __restrict__ Rout, void* __restrict__ fout)
{
  __shared__ u16 w2s[128 * 128];
  __shared__ u16 w3s[128 * 128];
  __shared__ u16 os[64 * 128];     // h2 staging, then output repack (wave-private)
  int t = threadIdx.x, lane = t & 63, wv = t >> 6;
  int m0 = wv * 16, mn = lane & 15, quad = lane >> 4;

  for (int i = t; i < 2048; i += 256){
    int row = i >> 4, cc = i & 15;
    *(uint4*)&w2s[swz16(row, cc)] = *(const uint4*)(cW2T + row * 128 + cc * 8);
    *(uint4*)&w3s[swz16(row, cc)] = *(const uint4*)(cW3T + row * 128 + cc * 8);
  }
  float b2v[8], b3v[8], gv[8], bev[8];
  #pragma unroll
  for (int j = 0; j < 8; j++){
    int c = j * 16 + mn;
    b2v[j] = bf2f(cb2[c]); b3v[j] = bf2f(cb3[c]);
    gv[j]  = bf2f(cg[c]);  bev[j] = bf2f(cbe[c]);
  }
  int isf = st->is_f32;
  __syncthreads();

  for (int tile = blockIdx.x; tile < N_TILES; tile += gridDim.x){
    int row0 = tile * 64;
    int arow = row0 + m0 + mn;

    bf8 a[4];
    const u32* hp = H + (size_t)arow * 64;
    #pragma unroll
    for (int s = 0; s < 4; s++) a[s] = ld_bf16_chunk(hp, s, quad);
    f4 acc[8];
    #pragma unroll
    for (int j = 0; j < 8; j++){ acc[j][0]=0.f; acc[j][1]=0.f; acc[j][2]=0.f; acc[j][3]=0.f; }
    gemm_ab(w2s, a, mn, quad, acc);

    #pragma unroll
    for (int j = 0; j < 8; j++){
      int c = j * 16 + mn;
      #pragma unroll
      for (int rg = 0; rg < 4; rg++){
        int row = m0 + quad * 4 + rg;
        os[row * 128 + ((c >> 3) ^ (row & 15)) * 8 + (c & 7)] = (u16)f2bf(gelu_f(acc[j][rg] + b2v[j]));
      }
    }
    __builtin_amdgcn_wave_barrier();

    #pragma unroll
    for (int s = 0; s < 4; s++) a[s] = *(const bf8*)&os[swz16(m0 + mn, s * 4 + quad)];
    #pragma unroll
    for (int j = 0; j < 8; j++){ acc[j][0]=0.f; acc[j][1]=0.f; acc[j][2]=0.f; acc[j][3]=0.f; }
    gemm_ab(w3s, a, mn, quad, acc);

    #pragma unroll
    for (int j = 0; j < 8; j++){
      #pragma unroll
      for (int rg = 0; rg < 4; rg++) acc[j][rg] += b3v[j];
    }
    float s1[4] = {0.f,0.f,0.f,0.f}, s2[4] = {0.f,0.f,0.f,0.f};
    #pragma unroll
    for (int j = 0; j < 8; j++){
      #pragma unroll
      for (int rg = 0; rg < 4; rg++){
        float v = acc[j][rg];
        s1[rg] += v; s2[rg] += v * v;
      }
    }
    #pragma unroll
    for (int o = 1; o < 16; o <<= 1){
      #pragma unroll
      for (int rg = 0; rg < 4; rg++){
        s1[rg] += __shfl_xor(s1[rg], o, 64);
        s2[rg] += __shfl_xor(s2[rg], o, 64);
      }
    }
    float mu[4], rs[4];
    #pragma unroll
    for (int rg = 0; rg < 4; rg++){
      mu[rg] = s1[rg] * 0.0078125f;
      float var = s2[rg] * 0.0078125f - mu[rg] * mu[rg];
      rs[rg] = rsqrtf(var + LN_EPS);
    }
    #pragma unroll
    for (int j = 0; j < 8; j++){
      #pragma unroll
      for (int rg = 0; rg < 4; rg++)
        acc[j][rg] = (acc[j][rg] - mu[rg]) * rs[rg] * gv[j] + bev[j];
    }

    if (!IS_DOWN && isf){
      float* fo = (float*)fout;
      #pragma unroll
      for (int j = 0; j < 8; j++){
        #pragma unroll
        for (int rg = 0; rg < 4; rg++)
          fo[(size_t)(row0 + m0 + quad * 4 + rg) * 128 + j * 16 + mn] = acc[j][rg];
      }
      continue;
    }

    __builtin_amdgcn_wave_barrier();
    #pragma unroll
    for (int j = 0; j < 8; j++){
      int c = j * 16 + mn;
      #pragma unroll
      for (int rg = 0; rg < 4; rg++){
        int row = m0 + quad * 4 + rg;
        os[row * 128 + ((c >> 3) ^ (row & 15)) * 8 + (c & 7)] = (u16)f2bf(acc[j][rg]);
      }
    }
    __builtin_amdgcn_wave_barrier();
    int rl = m0 + (lane >> 2), qt = lane & 3;
    u32 kp = IS_DOWN ? kept[row0 + rl] : 1u;
    u32* out = (IS_DOWN ? Rout : (u32*)fout) + (size_t)(row0 + rl) * 64;
    #pragma unroll
    for (int i = 0; i < 4; i++){
      int cc = qt * 4 + i;
      uint4 w = *(const uint4*)&os[swz16(rl, cc)];
      if (!kp){ w.x = 0; w.y = 0; w.z = 0; w.w = 0; }
      *(uint4*)(out + cc * 4) = w;
    }
    __builtin_amdgcn_wave_barrier();
  }
}

// ---------------- host launch ----------------

extern "C" void kernel_launch(void* const* d_in, const int* in_sizes, int n_in,
                              void* d_out, int out_size, void* d_ws, size_t ws_size,
                              hipStream_t stream)
{
  const void* x     = d_in[0];
  const int* eidx   = (const int*)d_in[1];
  const void* poolp = d_in[2];
  const int* senders = eidx;
  const int* receivers = eidx + N_EDGES;

  char* ws = (char*)d_ws;
  SelState* st = (SelState*)(ws + ST_OFF);
  u16*  canon  = (u16*) (ws + CANON_OFF);
  u32*  tots   = (u32*) (ws + PART_OFF);          // 4x256 per-pass bin totals
  u32*  gcur   = (u32*) (ws + PART_OFF + 4096);   // 256 bucket cursors
  u64*  keys   = (u64*) (ws + KEYS_OFF);
  u32*  off    = (u32*) (ws + KEYS_OFF);                 // overlays keys (dead after k_mark/k_tie)
  u32*  end    = (u32*) (ws + KEYS_OFF + (512u<<10));
  float* tval  = (float*)(ws + TVAL_OFF);
  u32*  kept   = (u32*) (ws + KEPT_OFF);
  u32*  Sbuf   = (u32*) (ws + SBUF_OFF);   // 32MB ws big-buffer (pairs, then messages)
  u32*  adj    = (u32*) (ws + ADJ_OFF);    // padded adj, 5MB
  u32*  pairs  = Sbuf;                     // 5MB padded staging (consumed before proj)
  u32*  Dbuf   = (u32*) d_out;             // 32MB d_out scratch region

  P16 ps;
  for (int i = 0; i < 16; i++) ps.q[i] = d_in[3 + i];

  k_detect<<<1, 256, 0, stream>>>((const u32*)x, st);
  k_canon<<<(CT_TOT + 255) / 256, 256, 0, stream>>>(ps, st, canon, tots, gcur);
  k_score<<<N_NODES / 4, 256, 0, stream>>>(x, poolp, st, keys, tval);
  for (int pass = 0; pass < 4; pass++)
    k_histp<<<256, 256, 0, stream>>>(keys, tots, pass);
  k_mark<<<N_NODES / 256, 256, 0, stream>>>(keys, tots, st, kept);
  k_tie<<<1, 256, 0, stream>>>(tots, st, kept);

  // ---- CSR build: bucketed 2-pass, fixed-capacity buckets ----
  k_bin<<<N_EDGES / 4096, 256, 0, stream>>>(senders, receivers, gcur, pairs);
  k_place<<<256, 256, 0, stream>>>(gcur, pairs, adj, off, end);

  // ---- down conv: S(ws) -> agg H(d_out) -> MLP -> R(ws) ----
  k_proj_down<<<768, 256, 0, stream>>>(x, tval, canon + CT_DW1, st, kept, Sbuf);
  k_agg<1><<<N_NODES / 16, 256, 0, stream>>>(Sbuf, off, end, adj, canon + C_DB1, kept, Dbuf);
  k_mlp<1><<<512, 256, 0, stream>>>(Dbuf,
      canon + CT_DW2, canon + C_DB2, canon + CT_DW3, canon + C_DB3,
      canon + C_DG, canon + C_DBE, kept, st, Sbuf, nullptr);

  // ---- up conv: R(ws) -> S2(d_out) -> agg H(ws) -> MLP -> d_out ----
  k_proj_up<<<512, 256, 0, stream>>>(Sbuf, x, canon + CT_UW1, st, Dbuf);
  k_agg<0><<<N_NODES / 16, 256, 0, stream>>>(Dbuf, off, end, adj, canon + C_UB1, kept, Sbuf);
  k_mlp<0><<<512, 256, 0, stream>>>(Sbuf,
      canon + CT_UW2, canon + C_UB2, canon + CT_UW3, canon + C_UB3,
      canon + C_UG, canon + C_UBE, kept, st, nullptr, d_out);
}

// Round 10
// 441.736 us; speedup vs baseline: 1.1967x; 1.0183x over previous
//
#include <hip/hip_runtime.h>

#define N_NODES 131072
#define N_EDGES 524288
#define K_TOP   65536
#define LN_EPS  1e-5f
#define N_TILES (N_NODES / 64)
#define BCAP    5120u            /* bucket capacity: mean 4096 + 16 sigma */

typedef unsigned int u32;
typedef unsigned short u16;
typedef unsigned long long u64;

typedef __attribute__((ext_vector_type(8))) short bf8;
typedef __attribute__((ext_vector_type(4))) float f4;

// ---- ws layout (requires ws >= 40 MB) ----
#define ST_OFF    0             // SelState (~52KB, reserve 64KB)
#define CANON_OFF (64u<<10)     // canon + transposed weights (~461KB) -> [64K, 576K)
#define PART_OFF  (576u<<10)    // tots[4][256] (4KB) + gcur[256] (1KB)
#define KEYS_OFF  (1u<<20)      // keys u64[N] = 1MB; after select reused as off/cnts u32[N]
#define TVAL_OFF  (2u<<20)      // N f32 = 512KB
#define KEPT_OFF  ((2u<<20)+(512u<<10)) // N u32 = 512KB
#define SBUF_OFF  (3u<<20)      // big buffer: N x 64 u32 = 32MB; pre-proj: pairs 5MB
#define ADJ_OFF   (35u<<20)     // padded adj u32[256*BCAP] = 5MB -> ends 40M

// Big-buffer ping-pong (d_out doubles as scratch):
//   CSR: pairs=ws.SBUF (consumed by k_place before k_proj_down reuses SBUF)
//   down: S=ws.SBUF -> k_agg<1> -> H=d_out -> k_mlp<1> -> R=ws.SBUF
//   up:   k_proj_up(R=ws) -> S2=d_out -> k_agg<0> -> H=ws.SBUF -> k_mlp<0> -> d_out
// Partitioned adjacency: each node's segment stores kept-source neighbors FIRST;
// cnts[n] = (kept_cnt<<16) | total_cnt. Down-agg reads only the kept prefix
// (the skipped rows are all-zero by construction -> dropping +0.0f is exact);
// up-agg reads the full segment. k_proj_down skips storing non-kept S rows
// (unreachable via the kept prefix).

// canonical parameter block offsets (bf16 elements)
#define C_DW1 0
#define C_DB1 16384
#define C_DW2 16512
#define C_DB2 32896
#define C_DW3 33024
#define C_DB3 49408
#define C_DG  49536
#define C_DBE 49664
#define C_UW1 49792
#define C_UB1 82560
#define C_UW2 82688
#define C_UB2 99072
#define C_UW3 99200
#define C_UB3 115584
#define C_UG  115712
#define C_UBE 115840
#define C_TOT 115968
// transposed weights WT[n][k] appended
#define CT_DW1 115968
#define CT_DW2 132352
#define CT_DW3 148736
#define CT_UW1 165120   /* [128][256] */
#define CT_UW2 197888
#define CT_UW3 214272
#define CT_TOT 230656

__device__ __forceinline__ float bflo(u32 u){ return __uint_as_float(u << 16); }
__device__ __forceinline__ float bfhi(u32 u){ return __uint_as_float(u & 0xFFFF0000u); }
__device__ __forceinline__ float bf2f(u16 v){ return __uint_as_float(((u32)v) << 16); }
__device__ __forceinline__ u32 f2bf(float f){
  u32 u = __float_as_uint(f);
  return (u + 0x7FFFu + ((u >> 16) & 1u)) >> 16;
}
__device__ __forceinline__ float gelu_f(float x){
  return 0.5f * x * (1.0f + erff(x * 0.7071067811865476f));
}
__device__ __forceinline__ float2 f2add(float2 a, float2 b){
  return make_float2(a.x + b.x, a.y + b.y);
}

// ---- swizzled LDS layout for [128 or 64 rows][16 chunks of 16B] matrices ----
__device__ __forceinline__ int swz16(int row, int cc){
  return row * 128 + ((cc ^ (row & 15)) * 8);
}

// A-fragment chunk builders (fragment lives in VGPRs; chunk cc = s*4+quad)
__device__ __forceinline__ bf8 ld_bf16_chunk(const u32* __restrict__ rowp, int s, int quad){
  uint4 v = *(const uint4*)(rowp + s * 16 + quad * 4);
  return __builtin_bit_cast(bf8, v);
}
__device__ __forceinline__ bf8 scale_bf16_chunk(const u32* __restrict__ rowp, int s, int quad, float tv){
  uint4 v = *(const uint4*)(rowp + s * 16 + quad * 4);
  uint4 q;
  q.x = f2bf(bflo(v.x) * tv) | (f2bf(bfhi(v.x) * tv) << 16);
  q.y = f2bf(bflo(v.y) * tv) | (f2bf(bfhi(v.y) * tv) << 16);
  q.z = f2bf(bflo(v.z) * tv) | (f2bf(bfhi(v.z) * tv) << 16);
  q.w = f2bf(bflo(v.w) * tv) | (f2bf(bfhi(v.w) * tv) << 16);
  return __builtin_bit_cast(bf8, q);
}
__device__ __forceinline__ bf8 cvt_f32_chunk(const float* __restrict__ rowp, int s, int quad, float tv){
  const float* p = rowp + s * 32 + quad * 8;
  float4 f0 = *(const float4*)p;
  float4 f1 = *(const float4*)(p + 4);
  uint4 q;
  q.x = f2bf(f0.x * tv) | (f2bf(f0.y * tv) << 16);
  q.y = f2bf(f0.z * tv) | (f2bf(f0.w * tv) << 16);
  q.z = f2bf(f1.x * tv) | (f2bf(f1.y * tv) << 16);
  q.w = f2bf(f1.z * tv) | (f2bf(f1.w * tv) << 16);
  return __builtin_bit_cast(bf8, q);
}

// 16x128 @ 128x128 GEMM step: A fragments in regs, B in swizzled LDS.
__device__ __forceinline__ void gemm_ab(const u16* ws, const bf8 a[4], int mn, int quad, f4 acc[8]){
  #pragma unroll
  for (int s = 0; s < 4; s++){
    #pragma unroll
    for (int j = 0; j < 8; j++){
      bf8 b = *(const bf8*)&ws[swz16(j * 16 + mn, s * 4 + quad)];
      acc[j] = __builtin_amdgcn_mfma_f32_16x16x32_bf16(a[s], b, acc[j], 0, 0, 0);
    }
  }
}

struct SelState {
  u64 prefix;
  u32 krem, eqcnt;
  int is_f32;
  u32 pad;
  double inv_norm;
  u32 eqlist[4096];
  u64 eqkey[4096];
};

struct P16 { const void* q[16]; };

// ---- shared radix-chain: suffix-scan tots[q] to get (chosen byte, new target) ----
__device__ __forceinline__ void chain_step(const u32* __restrict__ tots, int q,
                                           u32* sfx, u32* selb, int t,
                                           u64& pref, u32& target){
  sfx[t] = tots[q * 256 + t];
  __syncthreads();
  for (int o = 1; o < 256; o <<= 1){
    u32 x = (t + o < 256) ? sfx[t + o] : 0u;
    __syncthreads();
    sfx[t] += x;
    __syncthreads();
  }
  u32 above = (t == 255) ? 0u : sfx[t + 1];
  if (sfx[t] >= target && above < target){ selb[0] = (u32)t; selb[1] = target - above; }
  __syncthreads();
  pref = (pref << 8) | (u64)selb[0];
  target = selb[1];
  __syncthreads();
}

// ---------------- dtype detection + state init (fused) ----------------
__global__ void k_detect(const u32* __restrict__ xw, SelState* st){
  int t = threadIdx.x;
  int cnt = 0;
  for (int i = t; i < 4096; i += 256){
    u32 w = xw[(size_t)i * 2048];
    u32 e = (w >> 23) & 0xFFu;
    if (e >= 97u && e <= 135u) cnt++;
  }
  __shared__ int sh[256];
  sh[t] = cnt; __syncthreads();
  for (int o = 128; o > 0; o >>= 1){ if (t < o) sh[t] += sh[t+o]; __syncthreads(); }
  if (t == 0){
    st->is_f32 = (sh[0] >= 3072) ? 1 : 0;
    st->prefix = 0; st->krem = K_TOP; st->eqcnt = 0;
  }
}

// ---------------- canon + transposed weights + tots/gcur init (fused) ----------------
__global__ void k_canon(P16 ps, const SelState* __restrict__ st, u16* __restrict__ canon,
                        u32* __restrict__ tots, u32* __restrict__ gcur){
  int i = blockIdx.x * 256 + threadIdx.x;
  if (i < 1024) tots[i] = 0u;
  if (i < 256)  gcur[i] = (u32)i * BCAP;
  if (i >= CT_TOT) return;
  int isf = st->is_f32;
  if (i < C_TOT){
    const int off[17] = {C_DW1,C_DB1,C_DW2,C_DB2,C_DW3,C_DB3,C_DG,C_DBE,
                         C_UW1,C_UB1,C_UW2,C_UB2,C_UW3,C_UB3,C_UG,C_UBE,C_TOT};
    int seg = 0;
    #pragma unroll
    for (int s2 = 0; s2 < 16; s2++) if (i >= off[s2+1]) seg = s2 + 1;
    int j = i - off[seg];
    if (isf) canon[i] = (u16)f2bf(((const float*)ps.q[seg])[j]);
    else     canon[i] = ((const u16*)ps.q[seg])[j];
  } else {
    const int dst[7] = {CT_DW1, CT_DW2, CT_DW3, CT_UW1, CT_UW2, CT_UW3, CT_TOT};
    const int wq[6]  = {0, 2, 4, 8, 10, 12};   // dW1,dW2,dW3,uW1,uW2,uW3 in ps.q
    int g = i;
    int seg = 0;
    #pragma unroll
    for (int s2 = 0; s2 < 6; s2++) if (g >= dst[s2+1]) seg = s2 + 1;
    int loc = g - dst[seg];
    int K = (seg == 3) ? 256 : 128;
    int n = loc / K, k = loc % K;
    int src = k * 128 + n;
    if (isf) canon[g] = (u16)f2bf(((const float*)ps.q[wq[seg]])[src]);
    else     canon[g] = ((const u16*)ps.q[wq[seg]])[src];
  }
}

// ---------------- score (pool-norm fused; same pairwise order as old tree) ----------------
__global__ __launch_bounds__(256) void k_score(const void* __restrict__ xraw, const void* __restrict__ praw,
                        const SelState* __restrict__ st,
                        u64* __restrict__ keys, float* __restrict__ tval){
  int t = threadIdx.x, lane = t & 63, w = t >> 6;
  int n = blockIdx.x * 4 + w;
  double d, ps;
  if (st->is_f32){
    const float* xf = (const float*)xraw + (size_t)n * 128;
    const float* pf = (const float*)praw;
    double p0 = (double)pf[lane], p1 = (double)pf[64 + lane];
    d  = (double)xf[lane] * p0 + (double)xf[64 + lane] * p1;
    ps = p0 * p0 + p1 * p1;
  } else {
    const u32* xw = (const u32*)xraw + (size_t)n * 64;
    const u32* pw = (const u32*)praw;
    u32 xx = xw[lane], pv = pw[lane];
    double p0 = (double)bflo(pv), p1 = (double)bfhi(pv);
    d  = (double)bflo(xx) * p0 + (double)bfhi(xx) * p1;
    ps = p0 * p0 + p1 * p1;
  }
  for (int o = 32; o > 0; o >>= 1){
    d  += __shfl_down(d,  o, 64);
    ps += __shfl_down(ps, o, 64);
  }
  if (lane == 0){
    double sc = d * (1.0 / sqrt(ps));
    u64 u = (u64)__double_as_longlong(sc);
    u64 key = (u & 0x8000000000000000ULL) ? ~u : (u | 0x8000000000000000ULL);
    keys[n] = key;
    tval[n] = tanhf((float)sc);
  }
}

// ---------------- radix select: hist pass with in-kernel chain recompute ----------------
__global__ __launch_bounds__(256) void k_histp(const u64* __restrict__ keys,
                                               u32* __restrict__ tots, int pass){
  __shared__ u32 sfx[256];
  __shared__ u32 selb[2];
  __shared__ u32 h[256];
  int t = threadIdx.x;
  u64 pref = 0;
  u32 target = K_TOP;
  for (int q = 0; q < pass; q++)
    chain_step(tots, q, sfx, selb, t, pref, target);
  h[t] = 0;
  __syncthreads();
  int sh_d = 56 - 8 * pass;
  for (int n = blockIdx.x * 256 + t; n < N_NODES; n += 256 * 256){
    u64 k = keys[n];
    bool m = (pass == 0) ? true : ((k >> (sh_d + 8)) == pref);
    if (m) atomicAdd(&h[(u32)((k >> sh_d) & 255)], 1u);
  }
  __syncthreads();
  if (h[t]) atomicAdd(&tots[pass * 256 + t], h[t]);
}

// mark: recompute full 4-pass chain -> threshold T (top 32 bits)
__global__ __launch_bounds__(256) void k_mark(const u64* __restrict__ keys,
                                              const u32* __restrict__ tots,
                                              SelState* st, u32* __restrict__ kept){
  __shared__ u32 sfx[256];
  __shared__ u32 selb[2];
  int t = threadIdx.x;
  u64 pref = 0;
  u32 target = K_TOP;
  for (int q = 0; q < 4; q++)
    chain_step(tots, q, sfx, selb, t, pref, target);
  u32 T = (u32)pref;
  int n = blockIdx.x * 256 + t;
  u64 k = keys[n];
  u32 t32 = (u32)(k >> 32);
  kept[n] = (t32 > T) ? 1u : 0u;
  if (t32 == T){
    u32 i = atomicAdd(&st->eqcnt, 1u);
    if (i < 4096){ st->eqlist[i] = (u32)n; st->eqkey[i] = k; }
  }
}

__global__ __launch_bounds__(256) void k_tie(const u32* __restrict__ tots,
                                             SelState* st, u32* __restrict__ kept){
  __shared__ u32 sfx[256];
  __shared__ u32 selb[2];
  int t = threadIdx.x;
  u64 pref = 0;
  u32 target = K_TOP;
  for (int q = 0; q < 4; q++)
    chain_step(tots, q, sfx, selb, t, pref, target);
  u32 r = target;                       // krem after 4 passes
  u32 m = st->eqcnt; if (m > 4096) m = 4096;
  for (u32 i = t; i < m; i += 256){
    u64 ki = st->eqkey[i]; u32 ii = st->eqlist[i];
    u32 rank = 0;
    for (u32 j = 0; j < m; j++){
      u64 kj = st->eqkey[j];
      rank += (kj > ki || (kj == ki && st->eqlist[j] < ii)) ? 1u : 0u;
    }
    if (rank < r) kept[ii] = 1u;
  }
}

// ---------------- CSR build: fixed-capacity buckets ----------------
// Pass A: bin (target, neighbor) entries into 256 padded bucket regions via LDS,
// flush coalesced. payload = (nlocal[9b] << 17) | nbr[17b]
__global__ __launch_bounds__(256) void k_bin(const int* __restrict__ se, const int* __restrict__ re,
                                             u32* __restrict__ gcur, u32* __restrict__ pairs){
  __shared__ u32 cnt[256], sc[256], base[256], cur[256], gpos[256];
  __shared__ u32 stage[8192];
  int t = threadIdx.x;
  cnt[t] = 0;
  __syncthreads();
  int e0 = blockIdx.x * 4096;
  for (int i = t; i < 4096; i += 256){
    int s = se[e0 + i], r = re[e0 + i];
    atomicAdd(&cnt[(u32)r >> 9], 1u);
    atomicAdd(&cnt[(u32)s >> 9], 1u);
  }
  __syncthreads();
  sc[t] = cnt[t];
  __syncthreads();
  for (int o = 1; o < 256; o <<= 1){
    u32 x = (t >= o) ? sc[t - o] : 0u;
    __syncthreads();
    sc[t] += x;
    __syncthreads();
  }
  base[t] = sc[t] - cnt[t];
  cur[t] = base[t];
  gpos[t] = atomicAdd(&gcur[t], cnt[t]);
  __syncthreads();
  for (int i = t; i < 4096; i += 256){
    u32 s = (u32)se[e0 + i], r = (u32)re[e0 + i];
    u32 b1 = r >> 9, p1 = ((r & 511u) << 17) | s;
    u32 b2 = s >> 9, p2 = ((s & 511u) << 17) | r;
    stage[atomicAdd(&cur[b1], 1u)] = p1;
    stage[atomicAdd(&cur[b2], 1u)] = p2;
  }
  __syncthreads();
  int lane = t & 63, wv = t >> 6;
  for (int b = wv; b < 256; b += 4){
    u32 n = cnt[b], src = base[b], dst = gpos[b];
    for (u32 i = lane; i < n; i += 64)
      pairs[dst + i] = stage[src + i];
  }
}

// Pass B: one block per bucket. Count per-node (total + kept-source) in LDS,
// scan -> node offsets, write off[]/cnts[], place entries PARTITIONED:
// kept-source neighbors first, then non-kept. cnts = (kept<<16)|total.
__global__ __launch_bounds__(256) void k_place(const u32* __restrict__ gcur,
                                               const u32* __restrict__ pairs,
                                               const u32* __restrict__ kept,
                                               u32* __restrict__ adj,
                                               u32* __restrict__ off, u32* __restrict__ cnts){
  __shared__ u32 cnt[512], ck[512], curk[512], curn[512], lo[512], ex2[256];
  int b = blockIdx.x, t = threadIdx.x;
  u32 base = (u32)b * BCAP;
  u32 total = gcur[b] - base;
  cnt[t] = 0; cnt[t + 256] = 0;
  ck[t] = 0;  ck[t + 256] = 0;
  curk[t] = 0; curk[t + 256] = 0;
  curn[t] = 0; curn[t + 256] = 0;
  __syncthreads();
  for (u32 i = t; i < total; i += 256){
    u32 p = pairs[base + i];
    u32 nl = p >> 17, m = p & 0x1FFFFu;
    atomicAdd(&cnt[nl], 1u);
    if (kept[m]) atomicAdd(&ck[nl], 1u);
  }
  __syncthreads();
  u32 c0 = cnt[2 * t], c1 = cnt[2 * t + 1];
  ex2[t] = c0 + c1;
  __syncthreads();
  for (int o = 1; o < 256; o <<= 1){
    u32 x = (t >= o) ? ex2[t - o] : 0u;
    __syncthreads();
    ex2[t] += x;
    __syncthreads();
  }
  u32 e0 = ex2[t] - c0 - c1;           // exclusive prefix for node 2t
  int n0 = b * 512 + 2 * t;
  off[n0]     = base + e0;
  off[n0 + 1] = base + e0 + c0;
  cnts[n0]     = (ck[2 * t] << 16) | c0;
  cnts[n0 + 1] = (ck[2 * t + 1] << 16) | c1;
  lo[2 * t] = e0; lo[2 * t + 1] = e0 + c0;
  __syncthreads();
  for (u32 i = t; i < total; i += 256){
    u32 p = pairs[base + i];
    u32 nl = p >> 17, m = p & 0x1FFFFu;
    u32 slot;
    if (kept[m]) slot = base + lo[nl] + atomicAdd(&curk[nl], 1u);
    else         slot = base + lo[nl] + ck[nl] + atomicAdd(&curn[nl], 1u);
    adj[slot] = m;
  }
}

// ---------------- persistent MFMA GEMM kernels ----------------
// (weights staged once, barrier-free tile loop, wave-private os)

// S[n] = bf16(x[n]*tval[n] @ dW1), stored ONLY for kept n (non-kept rows are
// unreachable through the partitioned kept-prefix adjacency)
__global__ __launch_bounds__(256, 3) void k_proj_down(
    const void* __restrict__ xraw, const float* __restrict__ tval,
    const u16* __restrict__ W1T, const SelState* __restrict__ st,
    const u32* __restrict__ kept, u32* __restrict__ S)
{
  __shared__ u16 w1s[128 * 128];   // 32KB swizzled
  __shared__ u16 os[64 * 128];     // 16KB wave-private repack
  int t = threadIdx.x, lane = t & 63, wv = t >> 6;
  int m0 = wv * 16, mn = lane & 15, quad = lane >> 4;

  for (int i = t; i < 2048; i += 256){
    int row = i >> 4, cc = i & 15;
    *(uint4*)&w1s[swz16(row, cc)] = *(const uint4*)(W1T + row * 128 + cc * 8);
  }
  int isf = st->is_f32;
  __syncthreads();

  for (int tile = blockIdx.x; tile < N_TILES; tile += gridDim.x){
    int row0 = tile * 64;
    int arow = row0 + m0 + mn;
    float tv = tval[arow];
    bf8 a[4];
    if (isf){
      const float* xf = (const float*)xraw + (size_t)arow * 128;
      #pragma unroll
      for (int s = 0; s < 4; s++) a[s] = cvt_f32_chunk(xf, s, quad, tv);
    } else {
      const u32* xw = (const u32*)xraw + (size_t)arow * 64;
      #pragma unroll
      for (int s = 0; s < 4; s++) a[s] = scale_bf16_chunk(xw, s, quad, tv);
    }
    f4 acc[8];
    #pragma unroll
    for (int j = 0; j < 8; j++){ acc[j][0]=0.f; acc[j][1]=0.f; acc[j][2]=0.f; acc[j][3]=0.f; }
    gemm_ab(w1s, a, mn, quad, acc);

    #pragma unroll
    for (int j = 0; j < 8; j++){
      int c = j * 16 + mn;
      #pragma unroll
      for (int rg = 0; rg < 4; rg++){
        int row = m0 + quad * 4 + rg;
        os[row * 128 + ((c >> 3) ^ (row & 15)) * 8 + (c & 7)] = (u16)f2bf(acc[j][rg]);
      }
    }
    __builtin_amdgcn_wave_barrier();
    int rl = m0 + (lane >> 2), qt = lane & 3;
    u32 kp = kept[row0 + rl];
    u32* out = S + (size_t)(row0 + rl) * 64;
    if (kp){
      #pragma unroll
      for (int i = 0; i < 4; i++){
        int cc = qt * 4 + i;
        *(uint4*)(out + cc * 4) = *(const uint4*)&os[swz16(rl, cc)];
      }
    }
    __builtin_amdgcn_wave_barrier();  // readback before next tile overwrites os
  }
}

// S2[n] = bf16(R[n] @ uW1[0:128,:] + x[n] @ uW1[128:256,:])
__global__ __launch_bounds__(256, 2) void k_proj_up(
    const u32* __restrict__ R, const void* __restrict__ xraw,
    const u16* __restrict__ W1T, const SelState* __restrict__ st,
    u32* __restrict__ S2)
{
  __shared__ u16 was[128 * 128];   // uW1 rows, k 0:128
  __shared__ u16 wbs[128 * 128];   // uW1 rows, k 128:256
  __shared__ u16 os[64 * 128];
  int t = threadIdx.x, lane = t & 63, wv = t >> 6;
  int m0 = wv * 16, mn = lane & 15, quad = lane >> 4;

  for (int i = t; i < 2048; i += 256){
    int row = i >> 4, cc = i & 15;
    *(uint4*)&was[swz16(row, cc)] = *(const uint4*)(W1T + row * 256 + cc * 8);
    *(uint4*)&wbs[swz16(row, cc)] = *(const uint4*)(W1T + row * 256 + 128 + cc * 8);
  }
  int isf = st->is_f32;
  __syncthreads();

  for (int tile = blockIdx.x; tile < N_TILES; tile += gridDim.x){
    int row0 = tile * 64;
    int arow = row0 + m0 + mn;
    bf8 a[4];
    const u32* rp = R + (size_t)arow * 64;
    #pragma unroll
    for (int s = 0; s < 4; s++) a[s] = ld_bf16_chunk(rp, s, quad);
    f4 acc[8];
    #pragma unroll
    for (int j = 0; j < 8; j++){ acc[j][0]=0.f; acc[j][1]=0.f; acc[j][2]=0.f; acc[j][3]=0.f; }
    gemm_ab(was, a, mn, quad, acc);

    if (isf){
      const float* xf = (const float*)xraw + (size_t)arow * 128;
      #pragma unroll
      for (int s = 0; s < 4; s++) a[s] = cvt_f32_chunk(xf, s, quad, 1.0f);
    } else {
      const u32* xw = (const u32*)xraw + (size_t)arow * 64;
      #pragma unroll
      for (int s = 0; s < 4; s++) a[s] = ld_bf16_chunk(xw, s, quad);
    }
    gemm_ab(wbs, a, mn, quad, acc);

    #pragma unroll
    for (int j = 0; j < 8; j++){
      int c = j * 16 + mn;
      #pragma unroll
      for (int rg = 0; rg < 4; rg++){
        int row = m0 + quad * 4 + rg;
        os[row * 128 + ((c >> 3) ^ (row & 15)) * 8 + (c & 7)] = (u16)f2bf(acc[j][rg]);
      }
    }
    __builtin_amdgcn_wave_barrier();
    int rl = m0 + (lane >> 2), qt = lane & 3;
    u32* out = S2 + (size_t)(row0 + rl) * 64;
    #pragma unroll
    for (int i = 0; i < 4; i++){
      int cc = qt * 4 + i;
      *(uint4*)(out + cc * 4) = *(const uint4*)&os[swz16(rl, cc)];
    }
    __builtin_amdgcn_wave_barrier();
  }
}

// ---------------- dedicated high-occupancy pull-aggregation ----------------
// cnts[n] = (kept_cnt<<16)|total_cnt. DOWN iterates the kept prefix only.
template<int IS_DOWN>
__global__ __launch_bounds__(256, 4) void k_agg(
    const u32* __restrict__ Smsg, const u32* __restrict__ off, const u32* __restrict__ cnts,
    const u32* __restrict__ adj,
    const u16* __restrict__ cb1, const u32* __restrict__ kept,
    u32* __restrict__ H)
{
  int t = threadIdx.x, lane = t & 63, wv = t >> 6;
  float b1l = bf2f(cb1[2 * lane]), b1h = bf2f(cb1[2 * lane + 1]);
  int base = blockIdx.x * 16 + wv * 4;
  #pragma unroll 1
  for (int rr = 0; rr < 4; rr++){
    int n = base + rr;
    if (IS_DOWN && !kept[n]){ H[(size_t)n * 64 + lane] = 0u; continue; }
    u32 c = cnts[n];
    u32 jb = off[n];
    u32 je = jb + (IS_DOWN ? (c >> 16) : (c & 0xFFFFu));
    float2 a = make_float2(0.f, 0.f);
    u32 j = jb;
    for (; j + 8 <= je; j += 8){
      u32 e0 = adj[j],   e1 = adj[j+1], e2 = adj[j+2], e3 = adj[j+3];
      u32 e4 = adj[j+4], e5 = adj[j+5], e6 = adj[j+6], e7 = adj[j+7];
      u32 w0 = Smsg[(size_t)e0 * 64 + lane];
      u32 w1 = Smsg[(size_t)e1 * 64 + lane];
      u32 w2 = Smsg[(size_t)e2 * 64 + lane];
      u32 w3 = Smsg[(size_t)e3 * 64 + lane];
      u32 w4 = Smsg[(size_t)e4 * 64 + lane];
      u32 w5 = Smsg[(size_t)e5 * 64 + lane];
      u32 w6 = Smsg[(size_t)e6 * 64 + lane];
      u32 w7 = Smsg[(size_t)e7 * 64 + lane];
      float2 v0 = make_float2(bflo(w0), bfhi(w0));
      float2 v1 = make_float2(bflo(w1), bfhi(w1));
      float2 v2 = make_float2(bflo(w2), bfhi(w2));
      float2 v3 = make_float2(bflo(w3), bfhi(w3));
      float2 v4 = make_float2(bflo(w4), bfhi(w4));
      float2 v5 = make_float2(bflo(w5), bfhi(w5));
      float2 v6 = make_float2(bflo(w6), bfhi(w6));
      float2 v7 = make_float2(bflo(w7), bfhi(w7));
      a = f2add(a, f2add(f2add(f2add(v0, v1), f2add(v2, v3)),
                         f2add(f2add(v4, v5), f2add(v6, v7))));
    }
    for (; j + 4 <= je; j += 4){
      u32 e0 = adj[j], e1 = adj[j+1], e2 = adj[j+2], e3 = adj[j+3];
      u32 w0 = Smsg[(size_t)e0 * 64 + lane];
      u32 w1 = Smsg[(size_t)e1 * 64 + lane];
      u32 w2 = Smsg[(size_t)e2 * 64 + lane];
      u32 w3 = Smsg[(size_t)e3 * 64 + lane];
      float2 v0 = make_float2(bflo(w0), bfhi(w0));
      float2 v1 = make_float2(bflo(w1), bfhi(w1));
      float2 v2 = make_float2(bflo(w2), bfhi(w2));
      float2 v3 = make_float2(bflo(w3), bfhi(w3));
      a = f2add(a, f2add(f2add(v0, v1), f2add(v2, v3)));
    }
    for (; j < je; j++){
      u32 w = Smsg[(size_t)adj[j] * 64 + lane];
      a = f2add(a, make_float2(bflo(w), bfhi(w)));
    }
    H[(size_t)n * 64 + lane] = f2bf(gelu_f(a.x + b1l)) | (f2bf(gelu_f(a.y + b1h)) << 16);
  }
}

// ---------------- persistent MFMA MLP tail ----------------
template<int IS_DOWN>
__global__ __launch_bounds__(256, 2) void k_mlp(
    const u32* __restrict__ H,
    const u16* __restrict__ cW2T, const u16* __restrict__ cb2,
    const u16* __restrict__ cW3T, const u16* __restrict__ cb3,
    const u16* __restrict__ cg, const u16* __restrict__ cbe,
    const u32* __restrict__ kept, const SelState* __restrict__ st,
    u32* __restrict__ Rout, void* __restrict__ fout)
{
  __shared__ u16 w2s[128 * 128];
  __shared__ u16 w3s[128 * 128];
  __shared__ u16 os[64 * 128];     // h2 staging, then output repack (wave-private)
  int t = threadIdx.x, lane = t & 63, wv = t >> 6;
  int m0 = wv * 16, mn = lane & 15, quad = lane >> 4;

  for (int i = t; i < 2048; i += 256){
    int row = i >> 4, cc = i & 15;
    *(uint4*)&w2s[swz16(row, cc)] = *(const uint4*)(cW2T + row * 128 + cc * 8);
    *(uint4*)&w3s[swz16(row, cc)] = *(const uint4*)(cW3T + row * 128 + cc * 8);
  }
  float b2v[8], b3v[8], gv[8], bev[8];
  #pragma unroll
  for (int j = 0; j < 8; j++){
    int c = j * 16 + mn;
    b2v[j] = bf2f(cb2[c]); b3v[j] = bf2f(cb3[c]);
    gv[j]  = bf2f(cg[c]);  bev[j] = bf2f(cbe[c]);
  }
  int isf = st->is_f32;
  __syncthreads();

  for (int tile = blockIdx.x; tile < N_TILES; tile += gridDim.x){
    int row0 = tile * 64;
    int arow = row0 + m0 + mn;

    bf8 a[4];
    const u32* hp = H + (size_t)arow * 64;
    #pragma unroll
    for (int s = 0; s < 4; s++) a[s] = ld_bf16_chunk(hp, s, quad);
    f4 acc[8];
    #pragma unroll
    for (int j = 0; j < 8; j++){ acc[j][0]=0.f; acc[j][1]=0.f; acc[j][2]=0.f; acc[j][3]=0.f; }
    gemm_ab(w2s, a, mn, quad, acc);

    #pragma unroll
    for (int j = 0; j < 8; j++){
      int c = j * 16 + mn;
      #pragma unroll
      for (int rg = 0; rg < 4; rg++){
        int row = m0 + quad * 4 + rg;
        os[row * 128 + ((c >> 3) ^ (row & 15)) * 8 + (c & 7)] = (u16)f2bf(gelu_f(acc[j][rg] + b2v[j]));
      }
    }
    __builtin_amdgcn_wave_barrier();

    #pragma unroll
    for (int s = 0; s < 4; s++) a[s] = *(const bf8*)&os[swz16(m0 + mn, s * 4 + quad)];
    #pragma unroll
    for (int j = 0; j < 8; j++){ acc[j][0]=0.f; acc[j][1]=0.f; acc[j][2]=0.f; acc[j][3]=0.f; }
    gemm_ab(w3s, a, mn, quad, acc);

    #pragma unroll
    for (int j = 0; j < 8; j++){
      #pragma unroll
      for (int rg = 0; rg < 4; rg++) acc[j][rg] += b3v[j];
    }
    float s1[4] = {0.f,0.f,0.f,0.f}, s2[4] = {0.f,0.f,0.f,0.f};
    #pragma unroll
    for (int j = 0; j < 8; j++){
      #pragma unroll
      for (int rg = 0; rg < 4; rg++){
        float v = acc[j][rg];
        s1[rg] += v; s2[rg] += v * v;
      }
    }
    #pragma unroll
    for (int o = 1; o < 16; o <<= 1){
      #pragma unroll
      for (int rg = 0; rg < 4; rg++){
        s1[rg] += __shfl_xor(s1[rg], o, 64);
        s2[rg] += __shfl_xor(s2[rg], o, 64);
      }
    }
    float mu[4], rs[4];
    #pragma unroll
    for (int rg = 0; rg < 4; rg++){
      mu[rg] = s1[rg] * 0.0078125f;
      float var = s2[rg] * 0.0078125f - mu[rg] * mu[rg];
      rs[rg] = rsqrtf(var + LN_EPS);
    }
    #pragma unroll
    for (int j = 0; j < 8; j++){
      #pragma unroll
      for (int rg = 0; rg < 4; rg++)
        acc[j][rg] = (acc[j][rg] - mu[rg]) * rs[rg] * gv[j] + bev[j];
    }

    if (!IS_DOWN && isf){
      float* fo = (float*)fout;
      #pragma unroll
      for (int j = 0; j < 8; j++){
        #pragma unroll
        for (int rg = 0; rg < 4; rg++)
          fo[(size_t)(row0 + m0 + quad * 4 + rg) * 128 + j * 16 + mn] = acc[j][rg];
      }
      continue;
    }

    __builtin_amdgcn_wave_barrier();
    #pragma unroll
    for (int j = 0; j < 8; j++){
      int c = j * 16 + mn;
      #pragma unroll
      for (int rg = 0; rg < 4; rg++){
        int row = m0 + quad * 4 + rg;
        os[row * 128 + ((c >> 3) ^ (row & 15)) * 8 + (c & 7)] = (u16)f2bf(acc[j][rg]);
      }
    }
    __builtin_amdgcn_wave_barrier();
    int rl = m0 + (lane >> 2), qt = lane & 3;
    u32 kp = IS_DOWN ? kept[row0 + rl] : 1u;
    u32* out = (IS_DOWN ? Rout : (u32*)fout) + (size_t)(row0 + rl) * 64;
    #pragma unroll
    for (int i = 0; i < 4; i++){
      int cc = qt * 4 + i;
      uint4 w = *(const uint4*)&os[swz16(rl, cc)];
      if (!kp){ w.x = 0; w.y = 0; w.z = 0; w.w = 0; }
      *(uint4*)(out + cc * 4) = w;
    }
    __builtin_amdgcn_wave_barrier();
  }
}

// ---------------- host launch ----------------

extern "C" void kernel_launch(void* const* d_in, const int* in_sizes, int n_in,
                              void* d_out, int out_size, void* d_ws, size_t ws_size,
                              hipStream_t stream)
{
  const void* x     = d_in[0];
  const int* eidx   = (const int*)d_in[1];
  const void* poolp = d_in[2];
  const int* senders = eidx;
  const int* receivers = eidx + N_EDGES;

  char* ws = (char*)d_ws;
  SelState* st = (SelState*)(ws + ST_OFF);
  u16*  canon  = (u16*) (ws + CANON_OFF);
  u32*  tots   = (u32*) (ws + PART_OFF);          // 4x256 per-pass bin totals
  u32*  gcur   = (u32*) (ws + PART_OFF + 4096);   // 256 bucket cursors
  u64*  keys   = (u64*) (ws + KEYS_OFF);
  u32*  off    = (u32*) (ws + KEYS_OFF);                 // overlays keys (dead after select)
  u32*  cnts   = (u32*) (ws + KEYS_OFF + (512u<<10));    // (kept<<16)|total per node
  float* tval  = (float*)(ws + TVAL_OFF);
  u32*  kept   = (u32*) (ws + KEPT_OFF);
  u32*  Sbuf   = (u32*) (ws + SBUF_OFF);   // 32MB ws big-buffer (pairs, then messages)
  u32*  adj    = (u32*) (ws + ADJ_OFF);    // padded adj, 5MB
  u32*  pairs  = Sbuf;                     // 5MB padded staging (consumed before proj)
  u32*  Dbuf   = (u32*) d_out;             // 32MB d_out scratch region

  P16 ps;
  for (int i = 0; i < 16; i++) ps.q[i] = d_in[3 + i];

  k_detect<<<1, 256, 0, stream>>>((const u32*)x, st);
  k_canon<<<(CT_TOT + 255) / 256, 256, 0, stream>>>(ps, st, canon, tots, gcur);
  k_score<<<N_NODES / 4, 256, 0, stream>>>(x, poolp, st, keys, tval);
  for (int pass = 0; pass < 4; pass++)
    k_histp<<<256, 256, 0, stream>>>(keys, tots, pass);
  k_mark<<<N_NODES / 256, 256, 0, stream>>>(keys, tots, st, kept);
  k_tie<<<1, 256, 0, stream>>>(tots, st, kept);

  // ---- CSR build: bucketed 2-pass, fixed-capacity buckets, kept-partitioned ----
  k_bin<<<N_EDGES / 4096, 256, 0, stream>>>(senders, receivers, gcur, pairs);
  k_place<<<256, 256, 0, stream>>>(gcur, pairs, kept, adj, off, cnts);

  // ---- down conv: S(ws) -> agg H(d_out) -> MLP -> R(ws) ----
  k_proj_down<<<768, 256, 0, stream>>>(x, tval, canon + CT_DW1, st, kept, Sbuf);
  k_agg<1><<<N_NODES / 16, 256, 0, stream>>>(Sbuf, off, cnts, adj, canon + C_DB1, kept, Dbuf);
  k_mlp<1><<<512, 256, 0, stream>>>(Dbuf,
      canon + CT_DW2, canon + C_DB2, canon + CT_DW3, canon + C_DB3,
      canon + C_DG, canon + C_DBE, kept, st, Sbuf, nullptr);

  // ---- up conv: R(ws) -> S2(d_out) -> agg H(ws) -> MLP -> d_out ----
  k_proj_up<<<512, 256, 0, stream>>>(Sbuf, x, canon + CT_UW1, st, Dbuf);
  k_agg<0><<<N_NODES / 16, 256, 0, stream>>>(Dbuf, off, cnts, adj, canon + C_UB1, kept, Sbuf);
  k_mlp<0><<<512, 256, 0, stream>>>(Sbuf,
      canon + CT_UW2, canon + C_UB2, canon + CT_UW3, canon + C_UB3,
      canon + C_UG, canon + C_UBE, kept, st, nullptr, d_out);
}